// Round 5
// baseline (359.844 us; speedup 1.0000x reference)
//
#include <hip/hip_runtime.h>
#include <math.h>

#define NN 10000
#define EE 160000
#define ET 170000
#define FIN 256
#define HH 8
#define CC 64
#define HC 512
#define NCLS 40
#define ELLW 96

typedef unsigned short u16;
typedef unsigned int u32;
typedef _Float16 f16;
using f16x8 = __attribute__((ext_vector_type(8))) _Float16;
using f32x4 = __attribute__((ext_vector_type(4))) float;

#define MFMA16(a, b, c) __builtin_amdgcn_mfma_f32_16x16x32_f16((a), (b), (c), 0, 0, 0)

// ---------- ELL construction ----------
__global__ __launch_bounds__(256) void zero_int(int* p, int n) {
    int i = blockIdx.x * 256 + threadIdx.x;
    if (i < n) p[i] = 0;
}

__global__ __launch_bounds__(256) void scatter_ell(const int* __restrict__ ei,
                                                   int* __restrict__ cnt,
                                                   int* __restrict__ ell) {
    int e = blockIdx.x * 256 + threadIdx.x;
    if (e >= ET) return;
    int s, d;
    if (e < EE) { s = ei[e]; d = ei[EE + e]; }
    else        { s = e - EE; d = s; }          // self-loops appended
    int pos = atomicAdd(&cnt[d], 1);
    if (pos < ELLW) ell[(size_t)d * ELLW + pos] = s;
}

// ---------- all three weight transposes (fp32 [K][N] -> f16 [N][K]) ----------
__global__ __launch_bounds__(256) void convW_kernel(const float* __restrict__ W0,
                                                    const float* __restrict__ W1,
                                                    const float* __restrict__ W2,
                                                    f16* __restrict__ w0T,
                                                    f16* __restrict__ w1T,
                                                    f16* __restrict__ w2T) {
    int i = blockIdx.x * 256 + threadIdx.x;
    if (i < HC * FIN) {
        int n = i >> 8, k = i & 255;
        w0T[i] = (f16)W0[(size_t)k * HC + n];
    } else if (i < HC * FIN + HC * HC) {
        int j = i - HC * FIN;
        int n = j >> 9, k = j & 511;
        w1T[j] = (f16)W1[(size_t)k * HC + n];
    } else if (i < HC * FIN + HC * HC + NCLS * HC) {
        int j = i - HC * FIN - HC * HC;
        int n = j >> 9, k = j & 511;
        w2T[j] = (f16)W2[(size_t)k * NCLS + n];
    }
}

// ---------- shared epilogue: fused attention + hx2 store (BN=512, 4 waves) ----
// wave w owns cols [w*128, w*128+128) = heads 2w, 2w+1 exactly.
__device__ inline void epilogue_512(const f32x4 (&acc)[2][8], int bm, int w,
                                    int lane, int fm, int g,
                                    const float* __restrict__ a_src,
                                    const float* __restrict__ a_dst,
                                    f16* __restrict__ hx2,
                                    float* __restrict__ al_s,
                                    float* __restrict__ al_d) {
    float as_c[2][4], ad_c[2][4];
#pragma unroll
    for (int p = 0; p < 2; ++p)
#pragma unroll
        for (int q = 0; q < 4; ++q) {
            as_c[p][q] = a_src[(2 * w + p) * 64 + q * 16 + fm];
            ad_c[p][q] = a_dst[(2 * w + p) * 64 + q * 16 + fm];
        }
#pragma unroll
    for (int mt = 0; mt < 2; ++mt) {
#pragma unroll
        for (int r = 0; r < 4; ++r) {
            int row = bm + mt * 16 + g * 4 + r;
            float s0 = 0.f, s1 = 0.f, d0 = 0.f, d1 = 0.f;
#pragma unroll
            for (int q = 0; q < 4; ++q) {
                s0 += acc[mt][q][r] * as_c[0][q];
                d0 += acc[mt][q][r] * ad_c[0][q];
                s1 += acc[mt][4 + q][r] * as_c[1][q];
                d1 += acc[mt][4 + q][r] * ad_c[1][q];
            }
#pragma unroll
            for (int off = 1; off < 16; off <<= 1) {
                s0 += __shfl_xor(s0, off);
                d0 += __shfl_xor(d0, off);
                s1 += __shfl_xor(s1, off);
                d1 += __shfl_xor(d1, off);
            }
            if (fm == 0 && row < NN) {
                al_s[row * 8 + 2 * w]     = s0;
                al_d[row * 8 + 2 * w]     = d0;
                al_s[row * 8 + 2 * w + 1] = s1;
                al_d[row * 8 + 2 * w + 1] = d1;
            }
            if (row < NN) {
#pragma unroll
                for (int nt = 0; nt < 8; ++nt)
                    hx2[(size_t)row * HC + w * 128 + nt * 16 + fm] = (f16)acc[mt][nt][r];
            }
        }
    }
}

// ---------- layer 0: GEMM (A = f16(x) staged once) + fused attn ----------
__global__ __launch_bounds__(256) void g0_kernel(const float* __restrict__ x,
                                                 const f16* __restrict__ BT,
                                                 const float* __restrict__ a_src,
                                                 const float* __restrict__ a_dst,
                                                 f16* __restrict__ hx2,
                                                 float* __restrict__ al_s,
                                                 float* __restrict__ al_d) {
    __shared__ f16 As[32 * 264];   // persistent A tile [m][k], stride 264
    __shared__ f16 Bs[512 * 40];   // per-K-step B tile [n][k], stride 40
    int t = threadIdx.x;
    int bm = blockIdx.x * 32;
    int lane = t & 63, w = t >> 6;
    int fm = lane & 15, g = lane >> 4, ks = g * 8;

    // stage + convert A once (rows bm..bm+31, K=256)
#pragma unroll
    for (int j = 0; j < 8; ++j) {
        int c = j * 256 + t;
        int row = c >> 6, off = (c & 63) * 4;
        float4 v = make_float4(0.f, 0.f, 0.f, 0.f);
        if (bm + row < NN) v = *(const float4*)(x + (size_t)(bm + row) * FIN + off);
        ushort4 pk = make_ushort4(__builtin_bit_cast(u16, (f16)v.x),
                                  __builtin_bit_cast(u16, (f16)v.y),
                                  __builtin_bit_cast(u16, (f16)v.z),
                                  __builtin_bit_cast(u16, (f16)v.w));
        *(ushort4*)&As[row * 264 + off] = pk;
    }

    f32x4 acc[2][8] = {};
    uint4 rb[8];
    auto loadB = [&](int k0) {
#pragma unroll
        for (int j = 0; j < 8; ++j) {
            int c = j * 256 + t;
            rb[j] = *(const uint4*)(BT + (size_t)(c >> 2) * FIN + k0 + (c & 3) * 8);
        }
    };
    loadB(0);
    __syncthreads();    // As visible
    for (int k0 = 0; k0 < FIN; k0 += 32) {
#pragma unroll
        for (int j = 0; j < 8; ++j) {
            int c = j * 256 + t;
            *(uint4*)&Bs[(c >> 2) * 40 + (c & 3) * 8] = rb[j];
        }
        __syncthreads();
        if (k0 + 32 < FIN) loadB(k0 + 32);
        f16x8 a0 = *(const f16x8*)&As[fm * 264 + k0 + ks];
        f16x8 a1 = *(const f16x8*)&As[(16 + fm) * 264 + k0 + ks];
#pragma unroll
        for (int nt = 0; nt < 8; ++nt) {
            f16x8 b = *(const f16x8*)&Bs[((w * 8 + nt) * 16 + fm) * 40 + ks];
            acc[0][nt] = MFMA16(a0, b, acc[0][nt]);
            acc[1][nt] = MFMA16(a1, b, acc[1][nt]);
        }
        __syncthreads();
    }
    epilogue_512(acc, bm, w, lane, fm, g, a_src, a_dst, hx2, al_s, al_d);
}

// ---------- gather phase: aggregate 32 rows of prev layer into LDS A tile ----
__device__ inline void gather_rows(f16* __restrict__ As, int bm, int w, int lane,
                                   const f16* __restrict__ hxin,
                                   const float* __restrict__ als_in,
                                   const float* __restrict__ ald_in,
                                   const int* __restrict__ cnt,
                                   const int* __restrict__ ell,
                                   const float* __restrict__ bias) {
    int ch = lane * 8;           // this lane's 8 channels
    int h = lane >> 3;           // their head
    float bch[8];
#pragma unroll
    for (int j = 0; j < 8; ++j) bch[j] = bias[ch + j];
    for (int nd = w * 8; nd < w * 8 + 8; ++nd) {
        int gn = bm + nd;
        float a[8] = {0.f, 0.f, 0.f, 0.f, 0.f, 0.f, 0.f, 0.f};
        float den = 0.f;
        if (gn < NN) {
            float ald = ald_in[gn * 8 + h];
            int dg = cnt[gn]; if (dg > ELLW) dg = ELLW;
            const int* ep = ell + (size_t)gn * ELLW;
            int i = 0;
            for (; i + 2 <= dg; i += 2) {
                int s0 = ep[i], s1 = ep[i + 1];
                float e0 = als_in[s0 * 8 + h], e1 = als_in[s1 * 8 + h];
                uint4 v0 = *(const uint4*)(hxin + (size_t)s0 * HC + ch);
                uint4 v1 = *(const uint4*)(hxin + (size_t)s1 * HC + ch);
                e0 += ald; e0 = e0 > 0.f ? e0 : 0.2f * e0;
                e1 += ald; e1 = e1 > 0.f ? e1 : 0.2f * e1;
                float w0 = __expf(e0), w1 = __expf(e1);
                f16x8 f0 = __builtin_bit_cast(f16x8, v0);
                f16x8 f1 = __builtin_bit_cast(f16x8, v1);
#pragma unroll
                for (int j = 0; j < 8; ++j)
                    a[j] += w0 * (float)f0[j] + w1 * (float)f1[j];
                den += w0 + w1;
            }
            for (; i < dg; ++i) {
                int s0 = ep[i];
                float e0 = als_in[s0 * 8 + h] + ald;
                e0 = e0 > 0.f ? e0 : 0.2f * e0;
                float w0 = __expf(e0);
                uint4 v0 = *(const uint4*)(hxin + (size_t)s0 * HC + ch);
                f16x8 f0 = __builtin_bit_cast(f16x8, v0);
#pragma unroll
                for (int j = 0; j < 8; ++j) a[j] += w0 * (float)f0[j];
                den += w0;
            }
        }
        float inv = 1.f / (den + 1e-16f);
        f16x8 o;
#pragma unroll
        for (int j = 0; j < 8; ++j) {
            float v = (gn < NN) ? (a[j] * inv + bch[j]) : 0.f;
            v = v > 0.f ? v : expm1f(v);        // ELU
            o[j] = (f16)v;
        }
        *(uint4*)&As[nd * 520 + ch] = __builtin_bit_cast(uint4, o);
    }
}

// ---------- layers 1: fused aggregate(prev) + GEMM + attn ----------
__global__ __launch_bounds__(256) void agg_gemm_kernel(const f16* __restrict__ hxin,
                                                       const float* __restrict__ als_in,
                                                       const float* __restrict__ ald_in,
                                                       const int* __restrict__ cnt,
                                                       const int* __restrict__ ell,
                                                       const float* __restrict__ bias,
                                                       const f16* __restrict__ BT,
                                                       const float* __restrict__ a_src,
                                                       const float* __restrict__ a_dst,
                                                       f16* __restrict__ hxout,
                                                       float* __restrict__ als_out,
                                                       float* __restrict__ ald_out) {
    __shared__ f16 As[32 * 520];   // persistent aggregated A tile [m][k=512]
    __shared__ f16 Bs[512 * 40];
    int t = threadIdx.x;
    int bm = blockIdx.x * 32;
    int lane = t & 63, w = t >> 6;
    int fm = lane & 15, g = lane >> 4, ks = g * 8;

    gather_rows(As, bm, w, lane, hxin, als_in, ald_in, cnt, ell, bias);

    f32x4 acc[2][8] = {};
    uint4 rb[8];
    auto loadB = [&](int k0) {
#pragma unroll
        for (int j = 0; j < 8; ++j) {
            int c = j * 256 + t;
            rb[j] = *(const uint4*)(BT + (size_t)(c >> 2) * HC + k0 + (c & 3) * 8);
        }
    };
    loadB(0);
    __syncthreads();    // As (gathered) visible
    for (int k0 = 0; k0 < HC; k0 += 32) {
#pragma unroll
        for (int j = 0; j < 8; ++j) {
            int c = j * 256 + t;
            *(uint4*)&Bs[(c >> 2) * 40 + (c & 3) * 8] = rb[j];
        }
        __syncthreads();
        if (k0 + 32 < HC) loadB(k0 + 32);
        f16x8 a0 = *(const f16x8*)&As[fm * 520 + k0 + ks];
        f16x8 a1 = *(const f16x8*)&As[(16 + fm) * 520 + k0 + ks];
#pragma unroll
        for (int nt = 0; nt < 8; ++nt) {
            f16x8 b = *(const f16x8*)&Bs[((w * 8 + nt) * 16 + fm) * 40 + ks];
            acc[0][nt] = MFMA16(a0, b, acc[0][nt]);
            acc[1][nt] = MFMA16(a1, b, acc[1][nt]);
        }
        __syncthreads();
    }
    epilogue_512(acc, bm, w, lane, fm, g, a_src, a_dst, hxout, als_out, ald_out);
}

// ---------- layer 2: fused aggregate(prev) + GEMM(Nc=40) + attn ----------
__global__ __launch_bounds__(256) void agg_gemm2_kernel(const f16* __restrict__ hxin,
                                                        const float* __restrict__ als_in,
                                                        const float* __restrict__ ald_in,
                                                        const int* __restrict__ cnt,
                                                        const int* __restrict__ ell,
                                                        const float* __restrict__ bias,
                                                        const f16* __restrict__ BT,
                                                        const float* __restrict__ a_src2,
                                                        const float* __restrict__ a_dst2,
                                                        float* __restrict__ hx40,
                                                        float* __restrict__ als2,
                                                        float* __restrict__ ald2) {
    __shared__ f16 As[32 * 520];
    __shared__ f16 Bs[64 * 40];    // rows 40..63 zero
    __shared__ float pss[2][32];
    __shared__ float psd[2][32];
    int t = threadIdx.x;
    int bm = blockIdx.x * 32;
    int lane = t & 63, w = t >> 6;
    int fm = lane & 15, g = lane >> 4, ks = g * 8;
    int mt = w & 1, ntp = w >> 1;

    gather_rows(As, bm, w, lane, hxin, als_in, ald_in, cnt, ell, bias);

    f32x4 acc[2] = {};
    uint4 rb;
    auto loadB = [&](int k0) {
        int n = t >> 2, koff = (t & 3) * 8;
        rb = (n < NCLS) ? *(const uint4*)(BT + (size_t)n * HC + k0 + koff)
                        : make_uint4(0u, 0u, 0u, 0u);
    };
    loadB(0);
    __syncthreads();
    for (int k0 = 0; k0 < HC; k0 += 32) {
        *(uint4*)&Bs[(t >> 2) * 40 + (t & 3) * 8] = rb;
        __syncthreads();
        if (k0 + 32 < HC) loadB(k0 + 32);
        f16x8 a  = *(const f16x8*)&As[(mt * 16 + fm) * 520 + k0 + ks];
        f16x8 b0 = *(const f16x8*)&Bs[((ntp * 2 + 0) * 16 + fm) * 40 + ks];
        f16x8 b1 = *(const f16x8*)&Bs[((ntp * 2 + 1) * 16 + fm) * 40 + ks];
        acc[0] = MFMA16(a, b0, acc[0]);
        acc[1] = MFMA16(a, b1, acc[1]);
        __syncthreads();
    }

    // epilogue: store fp32 hx40 + cross-wave attn reduction (single head, C=40)
    float a2s[2], a2d[2];
#pragma unroll
    for (int j = 0; j < 2; ++j) {
        int col = (ntp * 2 + j) * 16 + fm;
        a2s[j] = (col < NCLS) ? a_src2[col] : 0.f;
        a2d[j] = (col < NCLS) ? a_dst2[col] : 0.f;
    }
#pragma unroll
    for (int r = 0; r < 4; ++r) {
        int lrow = mt * 16 + g * 4 + r;
        int row = bm + lrow;
        float s = acc[0][r] * a2s[0] + acc[1][r] * a2s[1];
        float d = acc[0][r] * a2d[0] + acc[1][r] * a2d[1];
#pragma unroll
        for (int off = 1; off < 16; off <<= 1) {
            s += __shfl_xor(s, off);
            d += __shfl_xor(d, off);
        }
        if (fm == 0) { pss[ntp][lrow] = s; psd[ntp][lrow] = d; }
        if (row < NN) {
#pragma unroll
            for (int j = 0; j < 2; ++j) {
                int col = (ntp * 2 + j) * 16 + fm;
                if (col < NCLS) hx40[(size_t)row * NCLS + col] = acc[j][r];
            }
        }
    }
    __syncthreads();
    if (t < 32 && bm + t < NN) {
        als2[bm + t] = pss[0][t] + pss[1][t];
        ald2[bm + t] = psd[0][t] + psd[1][t];
    }
}

// ---------- final aggregate (H=1, C=40), fp32, no ELU ----------
__global__ __launch_bounds__(64) void agg2_final(const float* __restrict__ hx40,
                                                 const float* __restrict__ als,
                                                 const float* __restrict__ aldp,
                                                 const int* __restrict__ cnt,
                                                 const int* __restrict__ ell,
                                                 const float* __restrict__ b2,
                                                 float* __restrict__ out) {
    int n = blockIdx.x;
    int c = threadIdx.x;
    float ald = aldp[n];
    int dg = cnt[n]; if (dg > ELLW) dg = ELLW;
    const int* ep = ell + (size_t)n * ELLW;
    float acc = 0.f, den = 0.f;
    int i = 0;
    for (; i + 4 <= dg; i += 4) {
        int s0 = ep[i], s1 = ep[i + 1], s2 = ep[i + 2], s3 = ep[i + 3];
        float e0 = als[s0], e1 = als[s1], e2 = als[s2], e3 = als[s3];
        float v0 = 0.f, v1 = 0.f, v2 = 0.f, v3 = 0.f;
        if (c < NCLS) {
            v0 = hx40[(size_t)s0 * NCLS + c];
            v1 = hx40[(size_t)s1 * NCLS + c];
            v2 = hx40[(size_t)s2 * NCLS + c];
            v3 = hx40[(size_t)s3 * NCLS + c];
        }
        e0 += ald; e0 = e0 > 0.f ? e0 : 0.2f * e0;
        e1 += ald; e1 = e1 > 0.f ? e1 : 0.2f * e1;
        e2 += ald; e2 = e2 > 0.f ? e2 : 0.2f * e2;
        e3 += ald; e3 = e3 > 0.f ? e3 : 0.2f * e3;
        float w0 = __expf(e0), w1 = __expf(e1), w2 = __expf(e2), w3 = __expf(e3);
        acc += w0 * v0 + w1 * v1 + w2 * v2 + w3 * v3;
        den += w0 + w1 + w2 + w3;
    }
    for (; i < dg; ++i) {
        int s = ep[i];
        float e = als[s] + ald;
        e = e > 0.f ? e : 0.2f * e;
        float wgt = __expf(e);
        if (c < NCLS) acc += wgt * hx40[(size_t)s * NCLS + c];
        den += wgt;
    }
    if (c < NCLS) out[(size_t)n * NCLS + c] = acc / (den + 1e-16f) + b2[c];
}

extern "C" void kernel_launch(void* const* d_in, const int* in_sizes, int n_in,
                              void* d_out, int out_size, void* d_ws, size_t ws_size,
                              hipStream_t stream) {
    const float* x   = (const float*)d_in[0];
    const int*   ei  = (const int*)  d_in[1];
    const float* W0  = (const float*)d_in[2];
    const float* as0 = (const float*)d_in[3];
    const float* ad0 = (const float*)d_in[4];
    const float* b0  = (const float*)d_in[5];
    const float* W1  = (const float*)d_in[6];
    const float* as1 = (const float*)d_in[7];
    const float* ad1 = (const float*)d_in[8];
    const float* b1  = (const float*)d_in[9];
    const float* W2  = (const float*)d_in[10];
    const float* as2 = (const float*)d_in[11];
    const float* ad2 = (const float*)d_in[12];
    const float* b2  = (const float*)d_in[13];
    float* out = (float*)d_out;

    char* p = (char*)d_ws;
    int* cnt  = (int*)p; p += 40064;
    int* ell  = (int*)p; p += (size_t)NN * ELLW * 4;    // 3.84 MB
    f16* w0T  = (f16*)p; p += HC * FIN * 2;
    f16* w1T  = (f16*)p; p += HC * HC * 2;
    f16* w2T  = (f16*)p; p += NCLS * HC * 2;
    f16* hxA  = (f16*)p; p += (size_t)NN * HC * 2;
    f16* hxB  = (f16*)p; p += (size_t)NN * HC * 2;
    float* hx40 = (float*)p; p += (size_t)NN * NCLS * 4;
    float* als0 = (float*)p; p += NN * HH * 4;
    float* ald0 = (float*)p; p += NN * HH * 4;
    float* als1 = (float*)p; p += NN * HH * 4;
    float* ald1 = (float*)p; p += NN * HH * 4;
    float* als2 = (float*)p; p += NN * 4;
    float* ald2 = (float*)p; p += NN * 4;

    const int NB = (NN + 31) / 32;   // 313 row-blocks

    zero_int<<<(NN + 255) / 256, 256, 0, stream>>>(cnt, NN);
    scatter_ell<<<(ET + 255) / 256, 256, 0, stream>>>(ei, cnt, ell);
    convW_kernel<<<(HC * FIN + HC * HC + NCLS * HC + 255) / 256, 256, 0, stream>>>(
        W0, W1, W2, w0T, w1T, w2T);

    g0_kernel<<<NB, 256, 0, stream>>>(x, w0T, as0, ad0, hxA, als0, ald0);
    agg_gemm_kernel<<<NB, 256, 0, stream>>>(hxA, als0, ald0, cnt, ell, b0,
                                            w1T, as1, ad1, hxB, als1, ald1);
    agg_gemm2_kernel<<<NB, 256, 0, stream>>>(hxB, als1, ald1, cnt, ell, b1,
                                             w2T, as2, ad2, hx40, als2, ald2);
    agg2_final<<<NN, 64, 0, stream>>>(hx40, als2, ald2, cnt, ell, b2, out);
}

// Round 6
// 296.305 us; speedup vs baseline: 1.2144x; 1.2144x over previous
//
#include <hip/hip_runtime.h>
#include <math.h>

#define NN 10000
#define EE 160000
#define ET 170000
#define FIN 256
#define HH 8
#define CC 64
#define HC 512
#define NCLS 40
#define ELLW 96

typedef unsigned short u16;
typedef unsigned int u32;
typedef _Float16 f16;
using f16x8 = __attribute__((ext_vector_type(8))) _Float16;
using f32x4 = __attribute__((ext_vector_type(4))) float;

#define MFMA16(a, b, c) __builtin_amdgcn_mfma_f32_16x16x32_f16((a), (b), (c), 0, 0, 0)

// ---------- ELL construction ----------
__global__ __launch_bounds__(256) void zero_int(int* p, int n) {
    int i = blockIdx.x * 256 + threadIdx.x;
    if (i < n) p[i] = 0;
}

__global__ __launch_bounds__(256) void scatter_ell(const int* __restrict__ ei,
                                                   int* __restrict__ cnt,
                                                   int* __restrict__ ell) {
    int e = blockIdx.x * 256 + threadIdx.x;
    if (e >= ET) return;
    int s, d;
    if (e < EE) { s = ei[e]; d = ei[EE + e]; }
    else        { s = e - EE; d = s; }          // self-loops appended
    int pos = atomicAdd(&cnt[d], 1);
    if (pos < ELLW) ell[(size_t)d * ELLW + pos] = s;
}

// ---------- all three weight transposes (fp32 [K][N] -> f16 [N][K]) ----------
__global__ __launch_bounds__(256) void convW_kernel(const float* __restrict__ W0,
                                                    const float* __restrict__ W1,
                                                    const float* __restrict__ W2,
                                                    f16* __restrict__ w0T,
                                                    f16* __restrict__ w1T,
                                                    f16* __restrict__ w2T) {
    int i = blockIdx.x * 256 + threadIdx.x;
    if (i < HC * FIN) {
        int n = i >> 8, k = i & 255;
        w0T[i] = (f16)W0[(size_t)k * HC + n];
    } else if (i < HC * FIN + HC * HC) {
        int j = i - HC * FIN;
        int n = j >> 9, k = j & 511;
        w1T[j] = (f16)W1[(size_t)k * HC + n];
    } else if (i < HC * FIN + HC * HC + NCLS * HC) {
        int j = i - HC * FIN - HC * HC;
        int n = j >> 9, k = j & 511;
        w2T[j] = (f16)W2[(size_t)k * NCLS + n];
    }
}

// ---------- shared epilogue: fused attention + hx2 store (BN=512, 4 waves) ----
// wave w owns cols [w*128, w*128+128) = heads 2w, 2w+1 exactly.
__device__ inline void epilogue_512(const f32x4 (&acc)[2][8], int bm, int w,
                                    int lane, int fm, int g,
                                    const float* __restrict__ a_src,
                                    const float* __restrict__ a_dst,
                                    f16* __restrict__ hx2,
                                    float* __restrict__ al_s,
                                    float* __restrict__ al_d) {
    float as_c[2][4], ad_c[2][4];
#pragma unroll
    for (int p = 0; p < 2; ++p)
#pragma unroll
        for (int q = 0; q < 4; ++q) {
            as_c[p][q] = a_src[(2 * w + p) * 64 + q * 16 + fm];
            ad_c[p][q] = a_dst[(2 * w + p) * 64 + q * 16 + fm];
        }
#pragma unroll
    for (int mt = 0; mt < 2; ++mt) {
#pragma unroll
        for (int r = 0; r < 4; ++r) {
            int row = bm + mt * 16 + g * 4 + r;
            float s0 = 0.f, s1 = 0.f, d0 = 0.f, d1 = 0.f;
#pragma unroll
            for (int q = 0; q < 4; ++q) {
                s0 += acc[mt][q][r] * as_c[0][q];
                d0 += acc[mt][q][r] * ad_c[0][q];
                s1 += acc[mt][4 + q][r] * as_c[1][q];
                d1 += acc[mt][4 + q][r] * ad_c[1][q];
            }
#pragma unroll
            for (int off = 1; off < 16; off <<= 1) {
                s0 += __shfl_xor(s0, off);
                d0 += __shfl_xor(d0, off);
                s1 += __shfl_xor(s1, off);
                d1 += __shfl_xor(d1, off);
            }
            if (fm == 0 && row < NN) {
                al_s[row * 8 + 2 * w]     = s0;
                al_d[row * 8 + 2 * w]     = d0;
                al_s[row * 8 + 2 * w + 1] = s1;
                al_d[row * 8 + 2 * w + 1] = d1;
            }
            if (row < NN) {
#pragma unroll
                for (int nt = 0; nt < 8; ++nt)
                    hx2[(size_t)row * HC + w * 128 + nt * 16 + fm] = (f16)acc[mt][nt][r];
            }
        }
    }
}

// ---------- GEMM [M,K] @ BT[512,K]^T + fused attn epilogue ----------
// BM=32 rows/block, BN=512 (full width). Per-K-step A/B staging (round-4
// proven: ~42 KB LDS -> 3 blocks/CU). AF32: A is fp32 (converted in staging).
template <int K, bool AF32>
__global__ __launch_bounds__(256) void gemm_attn(const void* __restrict__ Aptr,
                                                 const f16* __restrict__ BT,
                                                 const float* __restrict__ a_src,
                                                 const float* __restrict__ a_dst,
                                                 f16* __restrict__ hx2,
                                                 float* __restrict__ al_s,
                                                 float* __restrict__ al_d) {
    __shared__ f16 As[32 * 40];    // per-K-step [m][k] stride 40
    __shared__ f16 Bs[512 * 40];   // per-K-step [n][k] stride 40
    int t = threadIdx.x;
    int bm = blockIdx.x * 32;
    int lane = t & 63, w = t >> 6;
    int fm = lane & 15, g = lane >> 4, ks = g * 8;

    int arow = t >> 3, akoff = (t & 7) * 4;
    bool a_ok = (bm + arow) < NN;

    f32x4 acc[2][8] = {};
    float4 raf;
    uint2 rah;
    uint4 rb[8];

    auto loadA = [&](int k0) {
        if (AF32) {
            const float* A = (const float*)Aptr;
            raf = a_ok ? *(const float4*)(A + (size_t)(bm + arow) * K + k0 + akoff)
                       : make_float4(0.f, 0.f, 0.f, 0.f);
        } else {
            const f16* A = (const f16*)Aptr;
            rah = a_ok ? *(const uint2*)(A + (size_t)(bm + arow) * K + k0 + akoff)
                       : make_uint2(0u, 0u);
        }
    };
    auto loadB = [&](int k0) {
#pragma unroll
        for (int j = 0; j < 8; ++j) {
            int c = j * 256 + t;
            rb[j] = *(const uint4*)(BT + (size_t)(c >> 2) * K + k0 + (c & 3) * 8);
        }
    };

    loadA(0);
    loadB(0);
    for (int k0 = 0; k0 < K; k0 += 32) {
        if (AF32) {
            ushort4 pk = make_ushort4(__builtin_bit_cast(u16, (f16)raf.x),
                                      __builtin_bit_cast(u16, (f16)raf.y),
                                      __builtin_bit_cast(u16, (f16)raf.z),
                                      __builtin_bit_cast(u16, (f16)raf.w));
            *(ushort4*)&As[arow * 40 + akoff] = pk;
        } else {
            *(uint2*)&As[arow * 40 + akoff] = rah;
        }
#pragma unroll
        for (int j = 0; j < 8; ++j) {
            int c = j * 256 + t;
            *(uint4*)&Bs[(c >> 2) * 40 + (c & 3) * 8] = rb[j];
        }
        __syncthreads();
        if (k0 + 32 < K) { loadA(k0 + 32); loadB(k0 + 32); }
        f16x8 a0 = *(const f16x8*)&As[fm * 40 + ks];
        f16x8 a1 = *(const f16x8*)&As[(16 + fm) * 40 + ks];
#pragma unroll
        for (int nt = 0; nt < 8; ++nt) {
            f16x8 b = *(const f16x8*)&Bs[((w * 8 + nt) * 16 + fm) * 40 + ks];
            acc[0][nt] = MFMA16(a0, b, acc[0][nt]);
            acc[1][nt] = MFMA16(a1, b, acc[1][nt]);
        }
        __syncthreads();
    }
    epilogue_512(acc, bm, w, lane, fm, g, a_src, a_dst, hx2, al_s, al_d);
}

// ---------- layer 2: GEMM 512->40 + fused single-head attn epilogue ----------
__global__ __launch_bounds__(256) void gemm2_attn(const f16* __restrict__ A,
                                                  const f16* __restrict__ BT,
                                                  const float* __restrict__ a_src2,
                                                  const float* __restrict__ a_dst2,
                                                  float* __restrict__ hx40,
                                                  float* __restrict__ als2,
                                                  float* __restrict__ ald2) {
    __shared__ f16 As[32 * 40];
    __shared__ f16 Bs[64 * 40];    // rows 40..63 zero
    __shared__ float pss[2][32];
    __shared__ float psd[2][32];
    int t = threadIdx.x;
    int bm = blockIdx.x * 32;
    int lane = t & 63, w = t >> 6;
    int fm = lane & 15, g = lane >> 4, ks = g * 8;
    int mt = w & 1, ntp = w >> 1;

    int arow = t >> 3, akoff = (t & 7) * 4;
    bool a_ok = (bm + arow) < NN;

    f32x4 acc[2] = {};
    uint2 rah;
    uint4 rb;
    auto loadA = [&](int k0) {
        rah = a_ok ? *(const uint2*)(A + (size_t)(bm + arow) * HC + k0 + akoff)
                   : make_uint2(0u, 0u);
    };
    auto loadB = [&](int k0) {
        int n = t >> 2, koff = (t & 3) * 8;
        rb = (n < NCLS) ? *(const uint4*)(BT + (size_t)n * HC + k0 + koff)
                        : make_uint4(0u, 0u, 0u, 0u);
    };
    loadA(0);
    loadB(0);
    for (int k0 = 0; k0 < HC; k0 += 32) {
        *(uint2*)&As[arow * 40 + akoff] = rah;
        *(uint4*)&Bs[(t >> 2) * 40 + (t & 3) * 8] = rb;
        __syncthreads();
        if (k0 + 32 < HC) { loadA(k0 + 32); loadB(k0 + 32); }
        f16x8 a  = *(const f16x8*)&As[(mt * 16 + fm) * 40 + ks];
        f16x8 b0 = *(const f16x8*)&Bs[((ntp * 2 + 0) * 16 + fm) * 40 + ks];
        f16x8 b1 = *(const f16x8*)&Bs[((ntp * 2 + 1) * 16 + fm) * 40 + ks];
        acc[0] = MFMA16(a, b0, acc[0]);
        acc[1] = MFMA16(a, b1, acc[1]);
        __syncthreads();
    }

    float a2s[2], a2d[2];
#pragma unroll
    for (int j = 0; j < 2; ++j) {
        int col = (ntp * 2 + j) * 16 + fm;
        a2s[j] = (col < NCLS) ? a_src2[col] : 0.f;
        a2d[j] = (col < NCLS) ? a_dst2[col] : 0.f;
    }
#pragma unroll
    for (int r = 0; r < 4; ++r) {
        int lrow = mt * 16 + g * 4 + r;
        int row = bm + lrow;
        float s = acc[0][r] * a2s[0] + acc[1][r] * a2s[1];
        float d = acc[0][r] * a2d[0] + acc[1][r] * a2d[1];
#pragma unroll
        for (int off = 1; off < 16; off <<= 1) {
            s += __shfl_xor(s, off);
            d += __shfl_xor(d, off);
        }
        if (fm == 0) { pss[ntp][lrow] = s; psd[ntp][lrow] = d; }
        if (row < NN) {
#pragma unroll
            for (int j = 0; j < 2; ++j) {
                int col = (ntp * 2 + j) * 16 + fm;
                if (col < NCLS) hx40[(size_t)row * NCLS + col] = acc[j][r];
            }
        }
    }
    __syncthreads();
    if (t < 32 && bm + t < NN) {
        als2[bm + t] = pss[0][t] + pss[1][t];
        ald2[bm + t] = psd[0][t] + psd[1][t];
    }
}

// ---------- standalone aggregate (1 block/node, ELL), +bias +ELU -> f16 ------
__global__ __launch_bounds__(256) void agg_ell(const f16* __restrict__ hx2,
                                               const float* __restrict__ al_s,
                                               const float* __restrict__ al_d,
                                               const int* __restrict__ cnt,
                                               const int* __restrict__ ell,
                                               const float* __restrict__ bias,
                                               f16* __restrict__ outF) {
    int n = blockIdx.x;
    int tid = threadIdx.x;
    int ch = tid * 2;
    int h = ch >> 6;
    float ald = al_d[n * HH + h];
    int dg = cnt[n]; if (dg > ELLW) dg = ELLW;
    const int* ep = ell + (size_t)n * ELLW;
    float a0 = 0.f, a1 = 0.f, den = 0.f;
    int i = 0;
    for (; i + 4 <= dg; i += 4) {
        int s0 = ep[i], s1 = ep[i + 1], s2 = ep[i + 2], s3 = ep[i + 3];
        float e0 = al_s[s0 * HH + h], e1 = al_s[s1 * HH + h];
        float e2 = al_s[s2 * HH + h], e3 = al_s[s3 * HH + h];
        u32 v0 = *(const u32*)(hx2 + (size_t)s0 * HC + ch);
        u32 v1 = *(const u32*)(hx2 + (size_t)s1 * HC + ch);
        u32 v2 = *(const u32*)(hx2 + (size_t)s2 * HC + ch);
        u32 v3 = *(const u32*)(hx2 + (size_t)s3 * HC + ch);
        e0 += ald; e0 = e0 > 0.f ? e0 : 0.2f * e0;
        e1 += ald; e1 = e1 > 0.f ? e1 : 0.2f * e1;
        e2 += ald; e2 = e2 > 0.f ? e2 : 0.2f * e2;
        e3 += ald; e3 = e3 > 0.f ? e3 : 0.2f * e3;
        float w0 = __expf(e0), w1 = __expf(e1), w2 = __expf(e2), w3 = __expf(e3);
        float2 f0 = make_float2((float)__builtin_bit_cast(f16, (u16)(v0 & 0xFFFF)),
                                (float)__builtin_bit_cast(f16, (u16)(v0 >> 16)));
        float2 f1 = make_float2((float)__builtin_bit_cast(f16, (u16)(v1 & 0xFFFF)),
                                (float)__builtin_bit_cast(f16, (u16)(v1 >> 16)));
        float2 f2 = make_float2((float)__builtin_bit_cast(f16, (u16)(v2 & 0xFFFF)),
                                (float)__builtin_bit_cast(f16, (u16)(v2 >> 16)));
        float2 f3 = make_float2((float)__builtin_bit_cast(f16, (u16)(v3 & 0xFFFF)),
                                (float)__builtin_bit_cast(f16, (u16)(v3 >> 16)));
        a0 += w0 * f0.x + w1 * f1.x + w2 * f2.x + w3 * f3.x;
        a1 += w0 * f0.y + w1 * f1.y + w2 * f2.y + w3 * f3.y;
        den += w0 + w1 + w2 + w3;
    }
    for (; i < dg; ++i) {
        int s = ep[i];
        float e = al_s[s * HH + h] + ald;
        e = e > 0.f ? e : 0.2f * e;
        float wgt = __expf(e);
        u32 v = *(const u32*)(hx2 + (size_t)s * HC + ch);
        a0 += wgt * (float)__builtin_bit_cast(f16, (u16)(v & 0xFFFF));
        a1 += wgt * (float)__builtin_bit_cast(f16, (u16)(v >> 16));
        den += wgt;
    }
    float inv = 1.f / (den + 1e-16f);
    float o0 = a0 * inv + bias[ch];
    float o1 = a1 * inv + bias[ch + 1];
    o0 = o0 > 0.f ? o0 : expm1f(o0);          // ELU
    o1 = o1 > 0.f ? o1 : expm1f(o1);
    u32 pack = (u32)__builtin_bit_cast(u16, (f16)o0) |
               ((u32)__builtin_bit_cast(u16, (f16)o1) << 16);
    *(u32*)(outF + (size_t)n * HC + ch) = pack;
}

// ---------- final aggregate (H=1, C=40), fp32, no ELU ----------
__global__ __launch_bounds__(64) void agg2_final(const float* __restrict__ hx40,
                                                 const float* __restrict__ als,
                                                 const float* __restrict__ aldp,
                                                 const int* __restrict__ cnt,
                                                 const int* __restrict__ ell,
                                                 const float* __restrict__ b2,
                                                 float* __restrict__ out) {
    int n = blockIdx.x;
    int c = threadIdx.x;
    float ald = aldp[n];
    int dg = cnt[n]; if (dg > ELLW) dg = ELLW;
    const int* ep = ell + (size_t)n * ELLW;
    float acc = 0.f, den = 0.f;
    int i = 0;
    for (; i + 4 <= dg; i += 4) {
        int s0 = ep[i], s1 = ep[i + 1], s2 = ep[i + 2], s3 = ep[i + 3];
        float e0 = als[s0], e1 = als[s1], e2 = als[s2], e3 = als[s3];
        float v0 = 0.f, v1 = 0.f, v2 = 0.f, v3 = 0.f;
        if (c < NCLS) {
            v0 = hx40[(size_t)s0 * NCLS + c];
            v1 = hx40[(size_t)s1 * NCLS + c];
            v2 = hx40[(size_t)s2 * NCLS + c];
            v3 = hx40[(size_t)s3 * NCLS + c];
        }
        e0 += ald; e0 = e0 > 0.f ? e0 : 0.2f * e0;
        e1 += ald; e1 = e1 > 0.f ? e1 : 0.2f * e1;
        e2 += ald; e2 = e2 > 0.f ? e2 : 0.2f * e2;
        e3 += ald; e3 = e3 > 0.f ? e3 : 0.2f * e3;
        float w0 = __expf(e0), w1 = __expf(e1), w2 = __expf(e2), w3 = __expf(e3);
        acc += w0 * v0 + w1 * v1 + w2 * v2 + w3 * v3;
        den += w0 + w1 + w2 + w3;
    }
    for (; i < dg; ++i) {
        int s = ep[i];
        float e = als[s] + ald;
        e = e > 0.f ? e : 0.2f * e;
        float wgt = __expf(e);
        if (c < NCLS) acc += wgt * hx40[(size_t)s * NCLS + c];
        den += wgt;
    }
    if (c < NCLS) out[(size_t)n * NCLS + c] = acc / (den + 1e-16f) + b2[c];
}

extern "C" void kernel_launch(void* const* d_in, const int* in_sizes, int n_in,
                              void* d_out, int out_size, void* d_ws, size_t ws_size,
                              hipStream_t stream) {
    const float* x   = (const float*)d_in[0];
    const int*   ei  = (const int*)  d_in[1];
    const float* W0  = (const float*)d_in[2];
    const float* as0 = (const float*)d_in[3];
    const float* ad0 = (const float*)d_in[4];
    const float* b0  = (const float*)d_in[5];
    const float* W1  = (const float*)d_in[6];
    const float* as1 = (const float*)d_in[7];
    const float* ad1 = (const float*)d_in[8];
    const float* b1  = (const float*)d_in[9];
    const float* W2  = (const float*)d_in[10];
    const float* as2 = (const float*)d_in[11];
    const float* ad2 = (const float*)d_in[12];
    const float* b2  = (const float*)d_in[13];
    float* out = (float*)d_out;

    char* p = (char*)d_ws;
    int* cnt  = (int*)p; p += 40064;
    int* ell  = (int*)p; p += (size_t)NN * ELLW * 4;    // 3.84 MB
    f16* w0T  = (f16*)p; p += HC * FIN * 2;
    f16* w1T  = (f16*)p; p += HC * HC * 2;
    f16* w2T  = (f16*)p; p += NCLS * HC * 2;
    f16* hxA  = (f16*)p; p += (size_t)NN * HC * 2;
    f16* hxB  = (f16*)p; p += (size_t)NN * HC * 2;
    f16* fA   = (f16*)p; p += (size_t)NN * HC * 2;
    f16* fB   = (f16*)p; p += (size_t)NN * HC * 2;
    float* hx40 = (float*)p; p += (size_t)NN * NCLS * 4;
    float* als0 = (float*)p; p += NN * HH * 4;
    float* ald0 = (float*)p; p += NN * HH * 4;
    float* als1 = (float*)p; p += NN * HH * 4;
    float* ald1 = (float*)p; p += NN * HH * 4;
    float* als2 = (float*)p; p += NN * 4;
    float* ald2 = (float*)p; p += NN * 4;

    const int NB = (NN + 31) / 32;   // 313 row-blocks (all co-resident at 3/CU)

    zero_int<<<(NN + 255) / 256, 256, 0, stream>>>(cnt, NN);
    scatter_ell<<<(ET + 255) / 256, 256, 0, stream>>>(ei, cnt, ell);
    convW_kernel<<<(HC * FIN + HC * HC + NCLS * HC + 255) / 256, 256, 0, stream>>>(
        W0, W1, W2, w0T, w1T, w2T);

    // layer 0: GEMM(fp32 x -> f16 staged) + attn epilogue; then aggregate
    gemm_attn<FIN, true><<<NB, 256, 0, stream>>>(x, w0T, as0, ad0, hxA, als0, ald0);
    agg_ell<<<NN, 256, 0, stream>>>(hxA, als0, ald0, cnt, ell, b0, fA);
    // layer 1
    gemm_attn<HC, false><<<NB, 256, 0, stream>>>(fA, w1T, as1, ad1, hxB, als1, ald1);
    agg_ell<<<NN, 256, 0, stream>>>(hxB, als1, ald1, cnt, ell, b1, fB);
    // layer 2
    gemm2_attn<<<NB, 256, 0, stream>>>(fB, w2T, as2, ad2, hx40, als2, ald2);
    agg2_final<<<NN, 64, 0, stream>>>(hx40, als2, ald2, cnt, ell, b2, out);
}

// Round 7
// 254.633 us; speedup vs baseline: 1.4132x; 1.1637x over previous
//
#include <hip/hip_runtime.h>
#include <math.h>

#define NN 10000
#define EE 160000
#define ET 170000
#define FIN 256
#define HH 8
#define CC 64
#define HC 512
#define NCLS 40
#define ELLW 96

typedef unsigned short u16;
typedef unsigned int u32;
typedef _Float16 f16;
using f16x8 = __attribute__((ext_vector_type(8))) _Float16;
using f32x4 = __attribute__((ext_vector_type(4))) float;

#define MFMA16(a, b, c) __builtin_amdgcn_mfma_f32_16x16x32_f16((a), (b), (c), 0, 0, 0)

// ---------- ELL construction ----------
__global__ __launch_bounds__(256) void zero_int(int* p, int n) {
    int i = blockIdx.x * 256 + threadIdx.x;
    if (i < n) p[i] = 0;
}

__global__ __launch_bounds__(256) void scatter_ell(const int* __restrict__ ei,
                                                   int* __restrict__ cnt,
                                                   int* __restrict__ ell) {
    int e = blockIdx.x * 256 + threadIdx.x;
    if (e >= ET) return;
    int s, d;
    if (e < EE) { s = ei[e]; d = ei[EE + e]; }
    else        { s = e - EE; d = s; }          // self-loops appended
    int pos = atomicAdd(&cnt[d], 1);
    if (pos < ELLW) ell[(size_t)d * ELLW + pos] = s;
}

// ---------- all three weight transposes (fp32 [K][N] -> f16 [N][K]) ----------
__global__ __launch_bounds__(256) void convW_kernel(const float* __restrict__ W0,
                                                    const float* __restrict__ W1,
                                                    const float* __restrict__ W2,
                                                    f16* __restrict__ w0T,
                                                    f16* __restrict__ w1T,
                                                    f16* __restrict__ w2T) {
    int i = blockIdx.x * 256 + threadIdx.x;
    if (i < HC * FIN) {
        int n = i >> 8, k = i & 255;
        w0T[i] = (f16)W0[(size_t)k * HC + n];
    } else if (i < HC * FIN + HC * HC) {
        int j = i - HC * FIN;
        int n = j >> 9, k = j & 511;
        w1T[j] = (f16)W1[(size_t)k * HC + n];
    } else if (i < HC * FIN + HC * HC + NCLS * HC) {
        int j = i - HC * FIN - HC * HC;
        int n = j >> 9, k = j & 511;
        w2T[j] = (f16)W2[(size_t)k * NCLS + n];
    }
}

// ---------- GEMM [M,K] @ BT[512,K]^T + fused attn epilogue, BM=32 BN=128 ----
// grid (4, M/32) = 1252 blocks, ~14 KB LDS -> high occupancy (latency-bound
// fix for round 6's 313-block / 43.5 KB version). Wave w owns n-tiles
// {2w, 2w+1} = 32 cols = half a head; head partials combined via LDS.
template <int K, bool AF32>
__global__ __launch_bounds__(256) void gemm_attn(const void* __restrict__ Aptr,
                                                 const f16* __restrict__ BT,
                                                 const float* __restrict__ a_src,
                                                 const float* __restrict__ a_dst,
                                                 f16* __restrict__ hx2,
                                                 float* __restrict__ al_s,
                                                 float* __restrict__ al_d) {
    __shared__ f16 As[32 * 40];    // [m][k] stride 40 (2-way banks = free)
    __shared__ f16 Bs[128 * 40];   // [n][k]
    __shared__ float pss[4][32];
    __shared__ float psd[4][32];
    int t = threadIdx.x;
    int bn = blockIdx.x * 128, bm = blockIdx.y * 32;
    int lane = t & 63, w = t >> 6;
    int fm = lane & 15, g = lane >> 4, ks = g * 8;

    int arow = t >> 3, akoff = (t & 7) * 4;
    bool a_ok = (bm + arow) < NN;

    f32x4 acc[2][2] = {};
    float4 raf;
    uint2 rah;
    uint4 rb[2];

    auto loadA = [&](int k0) {
        if (AF32) {
            const float* A = (const float*)Aptr;
            raf = a_ok ? *(const float4*)(A + (size_t)(bm + arow) * K + k0 + akoff)
                       : make_float4(0.f, 0.f, 0.f, 0.f);
        } else {
            const f16* A = (const f16*)Aptr;
            rah = a_ok ? *(const uint2*)(A + (size_t)(bm + arow) * K + k0 + akoff)
                       : make_uint2(0u, 0u);
        }
    };
    auto loadB = [&](int k0) {
#pragma unroll
        for (int j = 0; j < 2; ++j) {
            int c = j * 256 + t;
            rb[j] = *(const uint4*)(BT + (size_t)(bn + (c >> 2)) * K + k0 + (c & 3) * 8);
        }
    };

    loadA(0);
    loadB(0);
    for (int k0 = 0; k0 < K; k0 += 32) {
        if (AF32) {
            ushort4 pk = make_ushort4(__builtin_bit_cast(u16, (f16)raf.x),
                                      __builtin_bit_cast(u16, (f16)raf.y),
                                      __builtin_bit_cast(u16, (f16)raf.z),
                                      __builtin_bit_cast(u16, (f16)raf.w));
            *(ushort4*)&As[arow * 40 + akoff] = pk;
        } else {
            *(uint2*)&As[arow * 40 + akoff] = rah;
        }
#pragma unroll
        for (int j = 0; j < 2; ++j) {
            int c = j * 256 + t;
            *(uint4*)&Bs[(c >> 2) * 40 + (c & 3) * 8] = rb[j];
        }
        __syncthreads();
        if (k0 + 32 < K) { loadA(k0 + 32); loadB(k0 + 32); }   // prefetch
        f16x8 a0 = *(const f16x8*)&As[fm * 40 + ks];
        f16x8 a1 = *(const f16x8*)&As[(16 + fm) * 40 + ks];
#pragma unroll
        for (int j = 0; j < 2; ++j) {
            f16x8 b = *(const f16x8*)&Bs[((w * 2 + j) * 16 + fm) * 40 + ks];
            acc[0][j] = MFMA16(a0, b, acc[0][j]);
            acc[1][j] = MFMA16(a1, b, acc[1][j]);
        }
        __syncthreads();
    }

    // epilogue: hx2 store + fused attention partials (C/D: col=lane&15,
    // row=(lane>>4)*4+reg)
    float as_c[2], ad_c[2];
#pragma unroll
    for (int j = 0; j < 2; ++j) {
        int col = bn + (w * 2 + j) * 16 + fm;
        as_c[j] = a_src[col];
        ad_c[j] = a_dst[col];
    }
#pragma unroll
    for (int mt = 0; mt < 2; ++mt) {
#pragma unroll
        for (int r = 0; r < 4; ++r) {
            int lrow = mt * 16 + g * 4 + r;
            int row = bm + lrow;
            float s = acc[mt][0][r] * as_c[0] + acc[mt][1][r] * as_c[1];
            float d = acc[mt][0][r] * ad_c[0] + acc[mt][1][r] * ad_c[1];
#pragma unroll
            for (int off = 1; off < 16; off <<= 1) {
                s += __shfl_xor(s, off);
                d += __shfl_xor(d, off);
            }
            if (fm == 0) { pss[w][lrow] = s; psd[w][lrow] = d; }
            if (row < NN) {
#pragma unroll
                for (int j = 0; j < 2; ++j)
                    hx2[(size_t)row * HC + bn + (w * 2 + j) * 16 + fm] =
                        (f16)acc[mt][j][r];
            }
        }
    }
    __syncthreads();
    if (t < 32 && bm + t < NN) {
        int h0 = bn >> 6;                    // block covers heads h0, h0+1
        al_s[(bm + t) * 8 + h0]     = pss[0][t] + pss[1][t];
        al_d[(bm + t) * 8 + h0]     = psd[0][t] + psd[1][t];
        al_s[(bm + t) * 8 + h0 + 1] = pss[2][t] + pss[3][t];
        al_d[(bm + t) * 8 + h0 + 1] = psd[2][t] + psd[3][t];
    }
}

// ---------- layer 2: GEMM 512->40 + fused single-head attn, BM=16 ----------
// grid 625 blocks, ~7 KB LDS. Wave w owns n-tile w (cols w*16..w*16+15).
__global__ __launch_bounds__(256) void gemm2_attn(const f16* __restrict__ A,
                                                  const f16* __restrict__ BT,
                                                  const float* __restrict__ a_src2,
                                                  const float* __restrict__ a_dst2,
                                                  float* __restrict__ hx40,
                                                  float* __restrict__ als2,
                                                  float* __restrict__ ald2) {
    __shared__ f16 As[16 * 40];
    __shared__ f16 Bs[64 * 40];    // rows 40..63 zero
    __shared__ float pss[4][16];
    __shared__ float psd[4][16];
    int t = threadIdx.x;
    int bm = blockIdx.x * 16;
    int lane = t & 63, w = t >> 6;
    int fm = lane & 15, g = lane >> 4, ks = g * 8;

    int arow = t >> 4, akoff = (t & 15) * 2;
    bool a_ok = (bm + arow) < NN;

    f32x4 acc = {};
    u32 rah;
    uint4 rb;
    auto loadA = [&](int k0) {
        rah = a_ok ? *(const u32*)(A + (size_t)(bm + arow) * HC + k0 + akoff) : 0u;
    };
    auto loadB = [&](int k0) {
        int n = t >> 2, koff = (t & 3) * 8;
        rb = (n < NCLS) ? *(const uint4*)(BT + (size_t)n * HC + k0 + koff)
                        : make_uint4(0u, 0u, 0u, 0u);
    };
    loadA(0);
    loadB(0);
    for (int k0 = 0; k0 < HC; k0 += 32) {
        *(u32*)&As[arow * 40 + akoff] = rah;
        *(uint4*)&Bs[(t >> 2) * 40 + (t & 3) * 8] = rb;
        __syncthreads();
        if (k0 + 32 < HC) { loadA(k0 + 32); loadB(k0 + 32); }
        f16x8 a = *(const f16x8*)&As[fm * 40 + ks];
        f16x8 b = *(const f16x8*)&Bs[(w * 16 + fm) * 40 + ks];
        acc = MFMA16(a, b, acc);
        __syncthreads();
    }

    int col = w * 16 + fm;
    float a2s = (col < NCLS) ? a_src2[col] : 0.f;
    float a2d = (col < NCLS) ? a_dst2[col] : 0.f;
#pragma unroll
    for (int r = 0; r < 4; ++r) {
        int lrow = g * 4 + r;
        int row = bm + lrow;
        float s = acc[r] * a2s;
        float d = acc[r] * a2d;
#pragma unroll
        for (int off = 1; off < 16; off <<= 1) {
            s += __shfl_xor(s, off);
            d += __shfl_xor(d, off);
        }
        if (fm == 0) { pss[w][lrow] = s; psd[w][lrow] = d; }
        if (row < NN && col < NCLS) hx40[(size_t)row * NCLS + col] = acc[r];
    }
    __syncthreads();
    if (t < 16 && bm + t < NN) {
        als2[bm + t] = pss[0][t] + pss[1][t] + pss[2][t] + pss[3][t];
        ald2[bm + t] = psd[0][t] + psd[1][t] + psd[2][t] + psd[3][t];
    }
}

// ---------- standalone aggregate (1 block/node, ELL), +bias +ELU -> f16 ------
__global__ __launch_bounds__(256) void agg_ell(const f16* __restrict__ hx2,
                                               const float* __restrict__ al_s,
                                               const float* __restrict__ al_d,
                                               const int* __restrict__ cnt,
                                               const int* __restrict__ ell,
                                               const float* __restrict__ bias,
                                               f16* __restrict__ outF) {
    int n = blockIdx.x;
    int tid = threadIdx.x;
    int ch = tid * 2;
    int h = ch >> 6;
    float ald = al_d[n * HH + h];
    int dg = cnt[n]; if (dg > ELLW) dg = ELLW;
    const int* ep = ell + (size_t)n * ELLW;
    float a0 = 0.f, a1 = 0.f, den = 0.f;
    int i = 0;
    for (; i + 4 <= dg; i += 4) {
        int s0 = ep[i], s1 = ep[i + 1], s2 = ep[i + 2], s3 = ep[i + 3];
        float e0 = al_s[s0 * HH + h], e1 = al_s[s1 * HH + h];
        float e2 = al_s[s2 * HH + h], e3 = al_s[s3 * HH + h];
        u32 v0 = *(const u32*)(hx2 + (size_t)s0 * HC + ch);
        u32 v1 = *(const u32*)(hx2 + (size_t)s1 * HC + ch);
        u32 v2 = *(const u32*)(hx2 + (size_t)s2 * HC + ch);
        u32 v3 = *(const u32*)(hx2 + (size_t)s3 * HC + ch);
        e0 += ald; e0 = e0 > 0.f ? e0 : 0.2f * e0;
        e1 += ald; e1 = e1 > 0.f ? e1 : 0.2f * e1;
        e2 += ald; e2 = e2 > 0.f ? e2 : 0.2f * e2;
        e3 += ald; e3 = e3 > 0.f ? e3 : 0.2f * e3;
        float w0 = __expf(e0), w1 = __expf(e1), w2 = __expf(e2), w3 = __expf(e3);
        float2 f0 = make_float2((float)__builtin_bit_cast(f16, (u16)(v0 & 0xFFFF)),
                                (float)__builtin_bit_cast(f16, (u16)(v0 >> 16)));
        float2 f1 = make_float2((float)__builtin_bit_cast(f16, (u16)(v1 & 0xFFFF)),
                                (float)__builtin_bit_cast(f16, (u16)(v1 >> 16)));
        float2 f2 = make_float2((float)__builtin_bit_cast(f16, (u16)(v2 & 0xFFFF)),
                                (float)__builtin_bit_cast(f16, (u16)(v2 >> 16)));
        float2 f3 = make_float2((float)__builtin_bit_cast(f16, (u16)(v3 & 0xFFFF)),
                                (float)__builtin_bit_cast(f16, (u16)(v3 >> 16)));
        a0 += w0 * f0.x + w1 * f1.x + w2 * f2.x + w3 * f3.x;
        a1 += w0 * f0.y + w1 * f1.y + w2 * f2.y + w3 * f3.y;
        den += w0 + w1 + w2 + w3;
    }
    for (; i < dg; ++i) {
        int s = ep[i];
        float e = al_s[s * HH + h] + ald;
        e = e > 0.f ? e : 0.2f * e;
        float wgt = __expf(e);
        u32 v = *(const u32*)(hx2 + (size_t)s * HC + ch);
        a0 += wgt * (float)__builtin_bit_cast(f16, (u16)(v & 0xFFFF));
        a1 += wgt * (float)__builtin_bit_cast(f16, (u16)(v >> 16));
        den += wgt;
    }
    float inv = 1.f / (den + 1e-16f);
    float o0 = a0 * inv + bias[ch];
    float o1 = a1 * inv + bias[ch + 1];
    o0 = o0 > 0.f ? o0 : expm1f(o0);          // ELU
    o1 = o1 > 0.f ? o1 : expm1f(o1);
    u32 pack = (u32)__builtin_bit_cast(u16, (f16)o0) |
               ((u32)__builtin_bit_cast(u16, (f16)o1) << 16);
    *(u32*)(outF + (size_t)n * HC + ch) = pack;
}

// ---------- final aggregate (H=1, C=40), fp32, no ELU ----------
__global__ __launch_bounds__(64) void agg2_final(const float* __restrict__ hx40,
                                                 const float* __restrict__ als,
                                                 const float* __restrict__ aldp,
                                                 const int* __restrict__ cnt,
                                                 const int* __restrict__ ell,
                                                 const float* __restrict__ b2,
                                                 float* __restrict__ out) {
    int n = blockIdx.x;
    int c = threadIdx.x;
    float ald = aldp[n];
    int dg = cnt[n]; if (dg > ELLW) dg = ELLW;
    const int* ep = ell + (size_t)n * ELLW;
    float acc = 0.f, den = 0.f;
    int i = 0;
    for (; i + 4 <= dg; i += 4) {
        int s0 = ep[i], s1 = ep[i + 1], s2 = ep[i + 2], s3 = ep[i + 3];
        float e0 = als[s0], e1 = als[s1], e2 = als[s2], e3 = als[s3];
        float v0 = 0.f, v1 = 0.f, v2 = 0.f, v3 = 0.f;
        if (c < NCLS) {
            v0 = hx40[(size_t)s0 * NCLS + c];
            v1 = hx40[(size_t)s1 * NCLS + c];
            v2 = hx40[(size_t)s2 * NCLS + c];
            v3 = hx40[(size_t)s3 * NCLS + c];
        }
        e0 += ald; e0 = e0 > 0.f ? e0 : 0.2f * e0;
        e1 += ald; e1 = e1 > 0.f ? e1 : 0.2f * e1;
        e2 += ald; e2 = e2 > 0.f ? e2 : 0.2f * e2;
        e3 += ald; e3 = e3 > 0.f ? e3 : 0.2f * e3;
        float w0 = __expf(e0), w1 = __expf(e1), w2 = __expf(e2), w3 = __expf(e3);
        acc += w0 * v0 + w1 * v1 + w2 * v2 + w3 * v3;
        den += w0 + w1 + w2 + w3;
    }
    for (; i < dg; ++i) {
        int s = ep[i];
        float e = als[s] + ald;
        e = e > 0.f ? e : 0.2f * e;
        float wgt = __expf(e);
        if (c < NCLS) acc += wgt * hx40[(size_t)s * NCLS + c];
        den += wgt;
    }
    if (c < NCLS) out[(size_t)n * NCLS + c] = acc / (den + 1e-16f) + b2[c];
}

extern "C" void kernel_launch(void* const* d_in, const int* in_sizes, int n_in,
                              void* d_out, int out_size, void* d_ws, size_t ws_size,
                              hipStream_t stream) {
    const float* x   = (const float*)d_in[0];
    const int*   ei  = (const int*)  d_in[1];
    const float* W0  = (const float*)d_in[2];
    const float* as0 = (const float*)d_in[3];
    const float* ad0 = (const float*)d_in[4];
    const float* b0  = (const float*)d_in[5];
    const float* W1  = (const float*)d_in[6];
    const float* as1 = (const float*)d_in[7];
    const float* ad1 = (const float*)d_in[8];
    const float* b1  = (const float*)d_in[9];
    const float* W2  = (const float*)d_in[10];
    const float* as2 = (const float*)d_in[11];
    const float* ad2 = (const float*)d_in[12];
    const float* b2  = (const float*)d_in[13];
    float* out = (float*)d_out;

    char* p = (char*)d_ws;
    int* cnt  = (int*)p; p += 40064;
    int* ell  = (int*)p; p += (size_t)NN * ELLW * 4;    // 3.84 MB
    f16* w0T  = (f16*)p; p += HC * FIN * 2;
    f16* w1T  = (f16*)p; p += HC * HC * 2;
    f16* w2T  = (f16*)p; p += NCLS * HC * 2;
    f16* hxA  = (f16*)p; p += (size_t)NN * HC * 2;
    f16* hxB  = (f16*)p; p += (size_t)NN * HC * 2;
    f16* fA   = (f16*)p; p += (size_t)NN * HC * 2;
    f16* fB   = (f16*)p; p += (size_t)NN * HC * 2;
    float* hx40 = (float*)p; p += (size_t)NN * NCLS * 4;
    float* als0 = (float*)p; p += NN * HH * 4;
    float* ald0 = (float*)p; p += NN * HH * 4;
    float* als1 = (float*)p; p += NN * HH * 4;
    float* ald1 = (float*)p; p += NN * HH * 4;
    float* als2 = (float*)p; p += NN * 4;
    float* ald2 = (float*)p; p += NN * 4;

    const int NBR = (NN + 31) / 32;   // 313 row-blocks (layers 0/1)
    const int NB2 = (NN + 15) / 16;   // 625 row-blocks (layer 2)

    zero_int<<<(NN + 255) / 256, 256, 0, stream>>>(cnt, NN);
    scatter_ell<<<(ET + 255) / 256, 256, 0, stream>>>(ei, cnt, ell);
    convW_kernel<<<(HC * FIN + HC * HC + NCLS * HC + 255) / 256, 256, 0, stream>>>(
        W0, W1, W2, w0T, w1T, w2T);

    dim3 gA(4, NBR);   // 1252 blocks
    // layer 0: GEMM(fp32 x -> f16 staged) + attn epilogue; then aggregate
    gemm_attn<FIN, true><<<gA, 256, 0, stream>>>(x, w0T, as0, ad0, hxA, als0, ald0);
    agg_ell<<<NN, 256, 0, stream>>>(hxA, als0, ald0, cnt, ell, b0, fA);
    // layer 1
    gemm_attn<HC, false><<<gA, 256, 0, stream>>>(fA, w1T, as1, ad1, hxB, als1, ald1);
    agg_ell<<<NN, 256, 0, stream>>>(hxB, als1, ald1, cnt, ell, b1, fB);
    // layer 2
    gemm2_attn<<<NB2, 256, 0, stream>>>(fB, w2T, as2, ad2, hx40, als2, ald2);
    agg2_final<<<NN, 64, 0, stream>>>(hx40, als2, ald2, cnt, ell, b2, out);
}

// Round 8
// 216.740 us; speedup vs baseline: 1.6603x; 1.1748x over previous
//
#include <hip/hip_runtime.h>
#include <math.h>

#define NN 10000
#define EE 160000
#define ET 170000
#define FIN 256
#define HH 8
#define CC 64
#define HC 512
#define NCLS 40
#define ELLW 96

typedef unsigned short u16;
typedef unsigned int u32;
typedef _Float16 f16;
using f16x8 = __attribute__((ext_vector_type(8))) _Float16;
using f32x4 = __attribute__((ext_vector_type(4))) float;

#define MFMA16(a, b, c) __builtin_amdgcn_mfma_f32_16x16x32_f16((a), (b), (c), 0, 0, 0)

// ---------- ELL construction ----------
__global__ __launch_bounds__(256) void zero_int(int* p, int n) {
    int i = blockIdx.x * 256 + threadIdx.x;
    if (i < n) p[i] = 0;
}

__global__ __launch_bounds__(256) void scatter_ell(const int* __restrict__ ei,
                                                   int* __restrict__ cnt,
                                                   int* __restrict__ ell) {
    int e = blockIdx.x * 256 + threadIdx.x;
    if (e >= ET) return;
    int s, d;
    if (e < EE) { s = ei[e]; d = ei[EE + e]; }
    else        { s = e - EE; d = s; }          // self-loops appended
    int pos = atomicAdd(&cnt[d], 1);
    if (pos < ELLW) ell[(size_t)d * ELLW + pos] = s;
}

// ---------- all three weight transposes (fp32 [K][N] -> f16 [N][K]) ----------
__global__ __launch_bounds__(256) void convW_kernel(const float* __restrict__ W0,
                                                    const float* __restrict__ W1,
                                                    const float* __restrict__ W2,
                                                    f16* __restrict__ w0T,
                                                    f16* __restrict__ w1T,
                                                    f16* __restrict__ w2T) {
    int i = blockIdx.x * 256 + threadIdx.x;
    if (i < HC * FIN) {
        int n = i >> 8, k = i & 255;
        w0T[i] = (f16)W0[(size_t)k * HC + n];
    } else if (i < HC * FIN + HC * HC) {
        int j = i - HC * FIN;
        int n = j >> 9, k = j & 511;
        w1T[j] = (f16)W1[(size_t)k * HC + n];
    } else if (i < HC * FIN + HC * HC + NCLS * HC) {
        int j = i - HC * FIN - HC * HC;
        int n = j >> 9, k = j & 511;
        w2T[j] = (f16)W2[(size_t)k * NCLS + n];
    }
}

// ---------- GEMM + fused attn: B-resident LDS, barrier-free K-loop ----------
// grid (4 head-pairs, 79 row-chunks of 128). Block = 8 waves; wave w owns
// rows [chunk*128 + w*16, +16) and a FULL head (64 cols) at a time.
// A-fragments load straight from global (natural MFMA layout), held in
// registers across both heads of the pair. B head-slice (64 x K) staged once
// per head into XOR-swizzled unpadded LDS (2-way banks = free). The K-loop
// has ZERO barriers: 64 back-to-back MFMAs per head per wave.
template <int K, bool AF32>
__global__ __launch_bounds__(512) void gemm_attn(const void* __restrict__ Aptr,
                                                 const f16* __restrict__ BT,
                                                 const float* __restrict__ a_src,
                                                 const float* __restrict__ a_dst,
                                                 f16* __restrict__ hx2,
                                                 float* __restrict__ al_s,
                                                 float* __restrict__ al_d) {
    constexpr int KK = K / 32;            // MFMA K-steps (16 or 8)
    constexpr int CH = K / 8;             // 16B chunks per B row (64 or 32)
    __shared__ f16 Bs[64 * K];            // 64 KB (K=512) / 32 KB (K=256)
    int t = threadIdx.x;
    int hp = blockIdx.x;                  // head pair
    int lane = t & 63, w = t >> 6;
    int fm = lane & 15, g = lane >> 4;
    int bm = blockIdx.y * 128 + w * 16;
    int row = bm + fm;
    bool rok = row < NN;

    // ---- A fragments for this wave's 16-row m-tile (kept for both heads)
    f16x8 af[KK];
    if (AF32) {
        const float* A = (const float*)Aptr;
#pragma unroll
        for (int kk = 0; kk < KK; ++kk) {
            float4 lo = make_float4(0.f, 0.f, 0.f, 0.f), hi = lo;
            if (rok) {
                const float* ap = A + (size_t)row * K + kk * 32 + g * 8;
                lo = *(const float4*)ap;
                hi = *(const float4*)(ap + 4);
            }
            f16x8 v;
            v[0] = (f16)lo.x; v[1] = (f16)lo.y; v[2] = (f16)lo.z; v[3] = (f16)lo.w;
            v[4] = (f16)hi.x; v[5] = (f16)hi.y; v[6] = (f16)hi.z; v[7] = (f16)hi.w;
            af[kk] = v;
        }
    } else {
        const f16* A = (const f16*)Aptr;
#pragma unroll
        for (int kk = 0; kk < KK; ++kk) {
            uint4 r = rok ? *(const uint4*)(A + (size_t)row * K + kk * 32 + g * 8)
                          : make_uint4(0u, 0u, 0u, 0u);
            af[kk] = __builtin_bit_cast(f16x8, r);
        }
    }

    for (int sl = 0; sl < 2; ++sl) {
        int h = hp * 2 + sl;
        // ---- stage head h's B (64 rows x K) into swizzled LDS
        const f16* bsrc = BT + (size_t)h * 64 * K;
        for (int c = t; c < 64 * CH; c += 512) {
            int brow = c / CH;
            int j = c - brow * CH;
            uint4 v = *(const uint4*)(bsrc + (size_t)brow * K + j * 8);
            *(uint4*)&Bs[(size_t)brow * K + ((j ^ (brow & 7)) * 8)] = v;
        }
        __syncthreads();

        f32x4 acc[4] = {};
#pragma unroll
        for (int kk = 0; kk < KK; ++kk) {
#pragma unroll
            for (int nt = 0; nt < 4; ++nt) {
                f16x8 b = *(const f16x8*)
                    &Bs[(nt * 16 + fm) * K + (((kk * 4 + g) ^ (fm & 7)) * 8)];
                acc[nt] = MFMA16(af[kk], b, acc[nt]);
            }
        }

        // ---- epilogue: hx2 store + wave-local attn reduction (full head)
        float asc[4], adc[4];
#pragma unroll
        for (int nt = 0; nt < 4; ++nt) {
            asc[nt] = a_src[h * 64 + nt * 16 + fm];
            adc[nt] = a_dst[h * 64 + nt * 16 + fm];
        }
#pragma unroll
        for (int r = 0; r < 4; ++r) {
            int orow = bm + g * 4 + r;          // C/D: row=(lane>>4)*4+reg
            float s = acc[0][r] * asc[0] + acc[1][r] * asc[1] +
                      acc[2][r] * asc[2] + acc[3][r] * asc[3];
            float d = acc[0][r] * adc[0] + acc[1][r] * adc[1] +
                      acc[2][r] * adc[2] + acc[3][r] * adc[3];
#pragma unroll
            for (int off = 1; off < 16; off <<= 1) {
                s += __shfl_xor(s, off);
                d += __shfl_xor(d, off);
            }
            if (orow < NN) {
                if (fm == 0) {
                    al_s[orow * 8 + h] = s;
                    al_d[orow * 8 + h] = d;
                }
#pragma unroll
                for (int nt = 0; nt < 4; ++nt)
                    hx2[(size_t)orow * HC + h * 64 + nt * 16 + fm] =
                        (f16)acc[nt][r];
            }
        }
        __syncthreads();   // all reads of Bs done before restaging for sl=1
    }
}

// ---------- layer 2: GEMM 512->40 + fused single-head attn, BM=16 ----------
__global__ __launch_bounds__(256) void gemm2_attn(const f16* __restrict__ A,
                                                  const f16* __restrict__ BT,
                                                  const float* __restrict__ a_src2,
                                                  const float* __restrict__ a_dst2,
                                                  float* __restrict__ hx40,
                                                  float* __restrict__ als2,
                                                  float* __restrict__ ald2) {
    __shared__ f16 As[16 * 40];
    __shared__ f16 Bs[64 * 40];    // rows 40..63 zero
    __shared__ float pss[4][16];
    __shared__ float psd[4][16];
    int t = threadIdx.x;
    int bm = blockIdx.x * 16;
    int lane = t & 63, w = t >> 6;
    int fm = lane & 15, g = lane >> 4, ks = g * 8;

    int arow = t >> 4, akoff = (t & 15) * 2;
    bool a_ok = (bm + arow) < NN;

    f32x4 acc = {};
    u32 rah;
    uint4 rb;
    auto loadA = [&](int k0) {
        rah = a_ok ? *(const u32*)(A + (size_t)(bm + arow) * HC + k0 + akoff) : 0u;
    };
    auto loadB = [&](int k0) {
        int n = t >> 2, koff = (t & 3) * 8;
        rb = (n < NCLS) ? *(const uint4*)(BT + (size_t)n * HC + k0 + koff)
                        : make_uint4(0u, 0u, 0u, 0u);
    };
    loadA(0);
    loadB(0);
    for (int k0 = 0; k0 < HC; k0 += 32) {
        *(u32*)&As[arow * 40 + akoff] = rah;
        *(uint4*)&Bs[(t >> 2) * 40 + (t & 3) * 8] = rb;
        __syncthreads();
        if (k0 + 32 < HC) { loadA(k0 + 32); loadB(k0 + 32); }
        f16x8 a = *(const f16x8*)&As[fm * 40 + ks];
        f16x8 b = *(const f16x8*)&Bs[(w * 16 + fm) * 40 + ks];
        acc = MFMA16(a, b, acc);
        __syncthreads();
    }

    int col = w * 16 + fm;
    float a2s = (col < NCLS) ? a_src2[col] : 0.f;
    float a2d = (col < NCLS) ? a_dst2[col] : 0.f;
#pragma unroll
    for (int r = 0; r < 4; ++r) {
        int lrow = g * 4 + r;
        int row = bm + lrow;
        float s = acc[r] * a2s;
        float d = acc[r] * a2d;
#pragma unroll
        for (int off = 1; off < 16; off <<= 1) {
            s += __shfl_xor(s, off);
            d += __shfl_xor(d, off);
        }
        if (fm == 0) { pss[w][lrow] = s; psd[w][lrow] = d; }
        if (row < NN && col < NCLS) hx40[(size_t)row * NCLS + col] = acc[r];
    }
    __syncthreads();
    if (t < 16 && bm + t < NN) {
        als2[bm + t] = pss[0][t] + pss[1][t] + pss[2][t] + pss[3][t];
        ald2[bm + t] = psd[0][t] + psd[1][t] + psd[2][t] + psd[3][t];
    }
}

// ---------- standalone aggregate (1 block/node, ELL), +bias +ELU -> f16 ------
__global__ __launch_bounds__(256) void agg_ell(const f16* __restrict__ hx2,
                                               const float* __restrict__ al_s,
                                               const float* __restrict__ al_d,
                                               const int* __restrict__ cnt,
                                               const int* __restrict__ ell,
                                               const float* __restrict__ bias,
                                               f16* __restrict__ outF) {
    int n = blockIdx.x;
    int tid = threadIdx.x;
    int ch = tid * 2;
    int h = ch >> 6;
    float ald = al_d[n * HH + h];
    int dg = cnt[n]; if (dg > ELLW) dg = ELLW;
    const int* ep = ell + (size_t)n * ELLW;
    float a0 = 0.f, a1 = 0.f, den = 0.f;
    int i = 0;
    for (; i + 4 <= dg; i += 4) {
        int s0 = ep[i], s1 = ep[i + 1], s2 = ep[i + 2], s3 = ep[i + 3];
        float e0 = al_s[s0 * HH + h], e1 = al_s[s1 * HH + h];
        float e2 = al_s[s2 * HH + h], e3 = al_s[s3 * HH + h];
        u32 v0 = *(const u32*)(hx2 + (size_t)s0 * HC + ch);
        u32 v1 = *(const u32*)(hx2 + (size_t)s1 * HC + ch);
        u32 v2 = *(const u32*)(hx2 + (size_t)s2 * HC + ch);
        u32 v3 = *(const u32*)(hx2 + (size_t)s3 * HC + ch);
        e0 += ald; e0 = e0 > 0.f ? e0 : 0.2f * e0;
        e1 += ald; e1 = e1 > 0.f ? e1 : 0.2f * e1;
        e2 += ald; e2 = e2 > 0.f ? e2 : 0.2f * e2;
        e3 += ald; e3 = e3 > 0.f ? e3 : 0.2f * e3;
        float w0 = __expf(e0), w1 = __expf(e1), w2 = __expf(e2), w3 = __expf(e3);
        float2 f0 = make_float2((float)__builtin_bit_cast(f16, (u16)(v0 & 0xFFFF)),
                                (float)__builtin_bit_cast(f16, (u16)(v0 >> 16)));
        float2 f1 = make_float2((float)__builtin_bit_cast(f16, (u16)(v1 & 0xFFFF)),
                                (float)__builtin_bit_cast(f16, (u16)(v1 >> 16)));
        float2 f2 = make_float2((float)__builtin_bit_cast(f16, (u16)(v2 & 0xFFFF)),
                                (float)__builtin_bit_cast(f16, (u16)(v2 >> 16)));
        float2 f3 = make_float2((float)__builtin_bit_cast(f16, (u16)(v3 & 0xFFFF)),
                                (float)__builtin_bit_cast(f16, (u16)(v3 >> 16)));
        a0 += w0 * f0.x + w1 * f1.x + w2 * f2.x + w3 * f3.x;
        a1 += w0 * f0.y + w1 * f1.y + w2 * f2.y + w3 * f3.y;
        den += w0 + w1 + w2 + w3;
    }
    for (; i < dg; ++i) {
        int s = ep[i];
        float e = al_s[s * HH + h] + ald;
        e = e > 0.f ? e : 0.2f * e;
        float wgt = __expf(e);
        u32 v = *(const u32*)(hx2 + (size_t)s * HC + ch);
        a0 += wgt * (float)__builtin_bit_cast(f16, (u16)(v & 0xFFFF));
        a1 += wgt * (float)__builtin_bit_cast(f16, (u16)(v >> 16));
        den += wgt;
    }
    float inv = 1.f / (den + 1e-16f);
    float o0 = a0 * inv + bias[ch];
    float o1 = a1 * inv + bias[ch + 1];
    o0 = o0 > 0.f ? o0 : expm1f(o0);          // ELU
    o1 = o1 > 0.f ? o1 : expm1f(o1);
    u32 pack = (u32)__builtin_bit_cast(u16, (f16)o0) |
               ((u32)__builtin_bit_cast(u16, (f16)o1) << 16);
    *(u32*)(outF + (size_t)n * HC + ch) = pack;
}

// ---------- final aggregate (H=1, C=40), fp32, no ELU ----------
__global__ __launch_bounds__(64) void agg2_final(const float* __restrict__ hx40,
                                                 const float* __restrict__ als,
                                                 const float* __restrict__ aldp,
                                                 const int* __restrict__ cnt,
                                                 const int* __restrict__ ell,
                                                 const float* __restrict__ b2,
                                                 float* __restrict__ out) {
    int n = blockIdx.x;
    int c = threadIdx.x;
    float ald = aldp[n];
    int dg = cnt[n]; if (dg > ELLW) dg = ELLW;
    const int* ep = ell + (size_t)n * ELLW;
    float acc = 0.f, den = 0.f;
    int i = 0;
    for (; i + 4 <= dg; i += 4) {
        int s0 = ep[i], s1 = ep[i + 1], s2 = ep[i + 2], s3 = ep[i + 3];
        float e0 = als[s0], e1 = als[s1], e2 = als[s2], e3 = als[s3];
        float v0 = 0.f, v1 = 0.f, v2 = 0.f, v3 = 0.f;
        if (c < NCLS) {
            v0 = hx40[(size_t)s0 * NCLS + c];
            v1 = hx40[(size_t)s1 * NCLS + c];
            v2 = hx40[(size_t)s2 * NCLS + c];
            v3 = hx40[(size_t)s3 * NCLS + c];
        }
        e0 += ald; e0 = e0 > 0.f ? e0 : 0.2f * e0;
        e1 += ald; e1 = e1 > 0.f ? e1 : 0.2f * e1;
        e2 += ald; e2 = e2 > 0.f ? e2 : 0.2f * e2;
        e3 += ald; e3 = e3 > 0.f ? e3 : 0.2f * e3;
        float w0 = __expf(e0), w1 = __expf(e1), w2 = __expf(e2), w3 = __expf(e3);
        acc += w0 * v0 + w1 * v1 + w2 * v2 + w3 * v3;
        den += w0 + w1 + w2 + w3;
    }
    for (; i < dg; ++i) {
        int s = ep[i];
        float e = als[s] + ald;
        e = e > 0.f ? e : 0.2f * e;
        float wgt = __expf(e);
        if (c < NCLS) acc += wgt * hx40[(size_t)s * NCLS + c];
        den += wgt;
    }
    if (c < NCLS) out[(size_t)n * NCLS + c] = acc / (den + 1e-16f) + b2[c];
}

extern "C" void kernel_launch(void* const* d_in, const int* in_sizes, int n_in,
                              void* d_out, int out_size, void* d_ws, size_t ws_size,
                              hipStream_t stream) {
    const float* x   = (const float*)d_in[0];
    const int*   ei  = (const int*)  d_in[1];
    const float* W0  = (const float*)d_in[2];
    const float* as0 = (const float*)d_in[3];
    const float* ad0 = (const float*)d_in[4];
    const float* b0  = (const float*)d_in[5];
    const float* W1  = (const float*)d_in[6];
    const float* as1 = (const float*)d_in[7];
    const float* ad1 = (const float*)d_in[8];
    const float* b1  = (const float*)d_in[9];
    const float* W2  = (const float*)d_in[10];
    const float* as2 = (const float*)d_in[11];
    const float* ad2 = (const float*)d_in[12];
    const float* b2  = (const float*)d_in[13];
    float* out = (float*)d_out;

    char* p = (char*)d_ws;
    int* cnt  = (int*)p; p += 40064;
    int* ell  = (int*)p; p += (size_t)NN * ELLW * 4;    // 3.84 MB
    f16* w0T  = (f16*)p; p += HC * FIN * 2;
    f16* w1T  = (f16*)p; p += HC * HC * 2;
    f16* w2T  = (f16*)p; p += NCLS * HC * 2;
    f16* hxA  = (f16*)p; p += (size_t)NN * HC * 2;
    f16* hxB  = (f16*)p; p += (size_t)NN * HC * 2;
    f16* fA   = (f16*)p; p += (size_t)NN * HC * 2;
    f16* fB   = (f16*)p; p += (size_t)NN * HC * 2;
    float* hx40 = (float*)p; p += (size_t)NN * NCLS * 4;
    float* als0 = (float*)p; p += NN * HH * 4;
    float* ald0 = (float*)p; p += NN * HH * 4;
    float* als1 = (float*)p; p += NN * HH * 4;
    float* ald1 = (float*)p; p += NN * HH * 4;
    float* als2 = (float*)p; p += NN * 4;
    float* ald2 = (float*)p; p += NN * 4;

    const int NBR = (NN + 127) / 128;   // 79 row-chunks (layers 0/1)
    const int NB2 = (NN + 15) / 16;     // 625 row-blocks (layer 2)

    zero_int<<<(NN + 255) / 256, 256, 0, stream>>>(cnt, NN);
    scatter_ell<<<(ET + 255) / 256, 256, 0, stream>>>(ei, cnt, ell);
    convW_kernel<<<(HC * FIN + HC * HC + NCLS * HC + 255) / 256, 256, 0, stream>>>(
        W0, W1, W2, w0T, w1T, w2T);

    dim3 gA(4, NBR);   // 4 head-pairs x 79 row-chunks = 316 blocks
    // layer 0: GEMM(fp32 x -> f16 frags) + attn epilogue; then aggregate
    gemm_attn<FIN, true><<<gA, 512, 0, stream>>>(x, w0T, as0, ad0, hxA, als0, ald0);
    agg_ell<<<NN, 256, 0, stream>>>(hxA, als0, ald0, cnt, ell, b0, fA);
    // layer 1
    gemm_attn<HC, false><<<gA, 512, 0, stream>>>(fA, w1T, as1, ad1, hxB, als1, ald1);
    agg_ell<<<NN, 256, 0, stream>>>(hxB, als1, ald1, cnt, ell, b1, fB);
    // layer 2
    gemm2_attn<<<NB2, 256, 0, stream>>>(fB, w2T, as2, ad2, hx40, als2, ald2);
    agg2_final<<<NN, 64, 0, stream>>>(hx40, als2, ald2, cnt, ell, b2, out);
}

// Round 9
// 207.477 us; speedup vs baseline: 1.7344x; 1.0446x over previous
//
#include <hip/hip_runtime.h>
#include <math.h>

#define NN 10000
#define EE 160000
#define ET 170000
#define FIN 256
#define HH 8
#define CC 64
#define HC 512
#define NCLS 40
#define ELLW 96

typedef unsigned short u16;
typedef unsigned int u32;
typedef _Float16 f16;
using f16x8 = __attribute__((ext_vector_type(8))) _Float16;
using f32x4 = __attribute__((ext_vector_type(4))) float;

#define MFMA16(a, b, c) __builtin_amdgcn_mfma_f32_16x16x32_f16((a), (b), (c), 0, 0, 0)

// ---------- ELL construction ----------
__global__ __launch_bounds__(256) void zero_int(int* p, int n) {
    int i = blockIdx.x * 256 + threadIdx.x;
    if (i < n) p[i] = 0;
}

__global__ __launch_bounds__(256) void scatter_ell(const int* __restrict__ ei,
                                                   int* __restrict__ cnt,
                                                   int* __restrict__ ell) {
    int e = blockIdx.x * 256 + threadIdx.x;
    if (e >= ET) return;
    int s, d;
    if (e < EE) { s = ei[e]; d = ei[EE + e]; }
    else        { s = e - EE; d = s; }          // self-loops appended
    int pos = atomicAdd(&cnt[d], 1);
    if (pos < ELLW) ell[(size_t)d * ELLW + pos] = s;
}

// ---------- all three weight transposes (fp32 [K][N] -> f16 [N][K]) ----------
__global__ __launch_bounds__(256) void convW_kernel(const float* __restrict__ W0,
                                                    const float* __restrict__ W1,
                                                    const float* __restrict__ W2,
                                                    f16* __restrict__ w0T,
                                                    f16* __restrict__ w1T,
                                                    f16* __restrict__ w2T) {
    int i = blockIdx.x * 256 + threadIdx.x;
    if (i < HC * FIN) {
        int n = i >> 8, k = i & 255;
        w0T[i] = (f16)W0[(size_t)k * HC + n];
    } else if (i < HC * FIN + HC * HC) {
        int j = i - HC * FIN;
        int n = j >> 9, k = j & 511;
        w1T[j] = (f16)W1[(size_t)k * HC + n];
    } else if (i < HC * FIN + HC * HC + NCLS * HC) {
        int j = i - HC * FIN - HC * HC;
        int n = j >> 9, k = j & 511;
        w2T[j] = (f16)W2[(size_t)k * NCLS + n];
    }
}

// ---------- GEMM + fused attn: B-resident LDS, barrier-free K-loop ----------
// grid (4 head-pairs, 79 row-chunks of 128). Block = 8 waves; wave w owns
// rows [chunk*128 + w*16, +16) and a FULL head (64 cols) at a time.
template <int K, bool AF32>
__global__ __launch_bounds__(512) void gemm_attn(const void* __restrict__ Aptr,
                                                 const f16* __restrict__ BT,
                                                 const float* __restrict__ a_src,
                                                 const float* __restrict__ a_dst,
                                                 f16* __restrict__ hx2,
                                                 float* __restrict__ al_s,
                                                 float* __restrict__ al_d) {
    constexpr int KK = K / 32;            // MFMA K-steps (16 or 8)
    constexpr int CH = K / 8;             // 16B chunks per B row (64 or 32)
    __shared__ f16 Bs[64 * K];            // 64 KB (K=512) / 32 KB (K=256)
    int t = threadIdx.x;
    int hp = blockIdx.x;                  // head pair
    int lane = t & 63, w = t >> 6;
    int fm = lane & 15, g = lane >> 4;
    int bm = blockIdx.y * 128 + w * 16;
    int row = bm + fm;
    bool rok = row < NN;

    // ---- A fragments for this wave's 16-row m-tile (kept for both heads)
    f16x8 af[KK];
    if (AF32) {
        const float* A = (const float*)Aptr;
#pragma unroll
        for (int kk = 0; kk < KK; ++kk) {
            float4 lo = make_float4(0.f, 0.f, 0.f, 0.f), hi = lo;
            if (rok) {
                const float* ap = A + (size_t)row * K + kk * 32 + g * 8;
                lo = *(const float4*)ap;
                hi = *(const float4*)(ap + 4);
            }
            f16x8 v;
            v[0] = (f16)lo.x; v[1] = (f16)lo.y; v[2] = (f16)lo.z; v[3] = (f16)lo.w;
            v[4] = (f16)hi.x; v[5] = (f16)hi.y; v[6] = (f16)hi.z; v[7] = (f16)hi.w;
            af[kk] = v;
        }
    } else {
        const f16* A = (const f16*)Aptr;
#pragma unroll
        for (int kk = 0; kk < KK; ++kk) {
            uint4 r = rok ? *(const uint4*)(A + (size_t)row * K + kk * 32 + g * 8)
                          : make_uint4(0u, 0u, 0u, 0u);
            af[kk] = __builtin_bit_cast(f16x8, r);
        }
    }

    for (int sl = 0; sl < 2; ++sl) {
        int h = hp * 2 + sl;
        // ---- stage head h's B (64 rows x K) into swizzled LDS
        const f16* bsrc = BT + (size_t)h * 64 * K;
        for (int c = t; c < 64 * CH; c += 512) {
            int brow = c / CH;
            int j = c - brow * CH;
            uint4 v = *(const uint4*)(bsrc + (size_t)brow * K + j * 8);
            *(uint4*)&Bs[(size_t)brow * K + ((j ^ (brow & 7)) * 8)] = v;
        }
        __syncthreads();

        f32x4 acc[4] = {};
#pragma unroll
        for (int kk = 0; kk < KK; ++kk) {
#pragma unroll
            for (int nt = 0; nt < 4; ++nt) {
                f16x8 b = *(const f16x8*)
                    &Bs[(nt * 16 + fm) * K + (((kk * 4 + g) ^ (fm & 7)) * 8)];
                acc[nt] = MFMA16(af[kk], b, acc[nt]);
            }
        }

        // ---- epilogue: hx2 store + wave-local attn reduction (full head)
        float asc[4], adc[4];
#pragma unroll
        for (int nt = 0; nt < 4; ++nt) {
            asc[nt] = a_src[h * 64 + nt * 16 + fm];
            adc[nt] = a_dst[h * 64 + nt * 16 + fm];
        }
#pragma unroll
        for (int r = 0; r < 4; ++r) {
            int orow = bm + g * 4 + r;          // C/D: row=(lane>>4)*4+reg
            float s = acc[0][r] * asc[0] + acc[1][r] * asc[1] +
                      acc[2][r] * asc[2] + acc[3][r] * asc[3];
            float d = acc[0][r] * adc[0] + acc[1][r] * adc[1] +
                      acc[2][r] * adc[2] + acc[3][r] * adc[3];
#pragma unroll
            for (int off = 1; off < 16; off <<= 1) {
                s += __shfl_xor(s, off);
                d += __shfl_xor(d, off);
            }
            if (orow < NN) {
                if (fm == 0) {
                    al_s[orow * 8 + h] = s;
                    al_d[orow * 8 + h] = d;
                }
#pragma unroll
                for (int nt = 0; nt < 4; ++nt)
                    hx2[(size_t)orow * HC + h * 64 + nt * 16 + fm] =
                        (f16)acc[nt][r];
            }
        }
        __syncthreads();   // all reads of Bs done before restaging for sl=1
    }
}

// ---------- layer 2: barrier-free B-resident GEMM 512->40 + fused attn ------
// grid 157 blocks x 4 waves; wave w owns rows bm+w*16..+16, all 40 cols.
// B (40x512) staged once into 48-row swizzled LDS; 48 MFMAs back-to-back.
__global__ __launch_bounds__(256) void gemm2_attn(const f16* __restrict__ A,
                                                  const f16* __restrict__ BT,
                                                  const float* __restrict__ a_src2,
                                                  const float* __restrict__ a_dst2,
                                                  float* __restrict__ hx40,
                                                  float* __restrict__ als2,
                                                  float* __restrict__ ald2) {
    __shared__ f16 Bs[48 * HC];    // 48 KB, rows 40..47 zero
    int t = threadIdx.x;
    int lane = t & 63, w = t >> 6;
    int fm = lane & 15, g = lane >> 4;
    int bm = blockIdx.x * 64 + w * 16;
    int row = bm + fm;
    bool rok = row < NN;

    // stage B swizzled (40 real rows + 8 zero pad rows)
    for (int c = t; c < 48 * 64; c += 256) {
        int brow = c >> 6, j = c & 63;
        uint4 v = make_uint4(0u, 0u, 0u, 0u);
        if (brow < NCLS) v = *(const uint4*)(BT + (size_t)brow * HC + j * 8);
        *(uint4*)&Bs[brow * HC + ((j ^ (brow & 7)) * 8)] = v;
    }

    // A fragments direct from global (natural MFMA layout)
    f16x8 af[16];
#pragma unroll
    for (int kk = 0; kk < 16; ++kk) {
        uint4 r = rok ? *(const uint4*)(A + (size_t)row * HC + kk * 32 + g * 8)
                      : make_uint4(0u, 0u, 0u, 0u);
        af[kk] = __builtin_bit_cast(f16x8, r);
    }
    __syncthreads();

    f32x4 acc[3] = {};
#pragma unroll
    for (int kk = 0; kk < 16; ++kk) {
#pragma unroll
        for (int nt = 0; nt < 3; ++nt) {
            f16x8 b = *(const f16x8*)
                &Bs[(nt * 16 + fm) * HC + (((kk * 4 + g) ^ (fm & 7)) * 8)];
            acc[nt] = MFMA16(af[kk], b, acc[nt]);
        }
    }

    // epilogue: wave-local single-head attn + hx40 store
    float a2s[3], a2d[3];
#pragma unroll
    for (int nt = 0; nt < 3; ++nt) {
        int col = nt * 16 + fm;
        a2s[nt] = (col < NCLS) ? a_src2[col] : 0.f;
        a2d[nt] = (col < NCLS) ? a_dst2[col] : 0.f;
    }
#pragma unroll
    for (int r = 0; r < 4; ++r) {
        int orow = bm + g * 4 + r;
        float s = acc[0][r] * a2s[0] + acc[1][r] * a2s[1] + acc[2][r] * a2s[2];
        float d = acc[0][r] * a2d[0] + acc[1][r] * a2d[1] + acc[2][r] * a2d[2];
#pragma unroll
        for (int off = 1; off < 16; off <<= 1) {
            s += __shfl_xor(s, off);
            d += __shfl_xor(d, off);
        }
        if (orow < NN) {
            if (fm == 0) { als2[orow] = s; ald2[orow] = d; }
#pragma unroll
            for (int nt = 0; nt < 3; ++nt) {
                int col = nt * 16 + fm;
                if (col < NCLS) hx40[(size_t)orow * NCLS + col] = acc[nt][r];
            }
        }
    }
}

// ---------- aggregate: 1 WAVE per node, uint4 (8ch) per lane ----------
__global__ __launch_bounds__(256) void agg_ell(const f16* __restrict__ hx2,
                                               const float* __restrict__ al_s,
                                               const float* __restrict__ al_d,
                                               const int* __restrict__ cnt,
                                               const int* __restrict__ ell,
                                               const float* __restrict__ bias,
                                               f16* __restrict__ outF) {
    int lane = threadIdx.x & 63, w = threadIdx.x >> 6;
    int n = blockIdx.x * 4 + w;
    if (n >= NN) return;
    int ch = lane * 8;          // 8 channels per lane; 64 lanes = 512 ch
    int h = lane >> 3;          // head of this lane's channels
    float ald = al_d[n * HH + h];
    int dg = cnt[n]; if (dg > ELLW) dg = ELLW;
    const int* ep = ell + (size_t)n * ELLW;
    float acc[8] = {0.f, 0.f, 0.f, 0.f, 0.f, 0.f, 0.f, 0.f};
    float den = 0.f;
    int i = 0;
    for (; i + 4 <= dg; i += 4) {
        int s0 = ep[i], s1 = ep[i + 1], s2 = ep[i + 2], s3 = ep[i + 3];
        float e0 = al_s[s0 * HH + h], e1 = al_s[s1 * HH + h];
        float e2 = al_s[s2 * HH + h], e3 = al_s[s3 * HH + h];
        uint4 v0 = *(const uint4*)(hx2 + (size_t)s0 * HC + ch);
        uint4 v1 = *(const uint4*)(hx2 + (size_t)s1 * HC + ch);
        uint4 v2 = *(const uint4*)(hx2 + (size_t)s2 * HC + ch);
        uint4 v3 = *(const uint4*)(hx2 + (size_t)s3 * HC + ch);
        e0 += ald; e0 = e0 > 0.f ? e0 : 0.2f * e0;
        e1 += ald; e1 = e1 > 0.f ? e1 : 0.2f * e1;
        e2 += ald; e2 = e2 > 0.f ? e2 : 0.2f * e2;
        e3 += ald; e3 = e3 > 0.f ? e3 : 0.2f * e3;
        float w0 = __expf(e0), w1 = __expf(e1), w2 = __expf(e2), w3 = __expf(e3);
        f16x8 f0 = __builtin_bit_cast(f16x8, v0);
        f16x8 f1 = __builtin_bit_cast(f16x8, v1);
        f16x8 f2 = __builtin_bit_cast(f16x8, v2);
        f16x8 f3 = __builtin_bit_cast(f16x8, v3);
#pragma unroll
        for (int j = 0; j < 8; ++j)
            acc[j] += w0 * (float)f0[j] + w1 * (float)f1[j] +
                      w2 * (float)f2[j] + w3 * (float)f3[j];
        den += w0 + w1 + w2 + w3;
    }
    for (; i < dg; ++i) {
        int s = ep[i];
        float e = al_s[s * HH + h] + ald;
        e = e > 0.f ? e : 0.2f * e;
        float wgt = __expf(e);
        uint4 v = *(const uint4*)(hx2 + (size_t)s * HC + ch);
        f16x8 f = __builtin_bit_cast(f16x8, v);
#pragma unroll
        for (int j = 0; j < 8; ++j) acc[j] += wgt * (float)f[j];
        den += wgt;
    }
    float inv = 1.f / (den + 1e-16f);
    float4 b0v = *(const float4*)(bias + ch);
    float4 b1v = *(const float4*)(bias + ch + 4);
    float bb[8] = {b0v.x, b0v.y, b0v.z, b0v.w, b1v.x, b1v.y, b1v.z, b1v.w};
    f16x8 o;
#pragma unroll
    for (int j = 0; j < 8; ++j) {
        float v = acc[j] * inv + bb[j];
        v = v > 0.f ? v : expm1f(v);            // ELU
        o[j] = (f16)v;
    }
    *(uint4*)(outF + (size_t)n * HC + ch) = __builtin_bit_cast(uint4, o);
}

// ---------- final aggregate (H=1, C=40), fp32, no ELU ----------
__global__ __launch_bounds__(64) void agg2_final(const float* __restrict__ hx40,
                                                 const float* __restrict__ als,
                                                 const float* __restrict__ aldp,
                                                 const int* __restrict__ cnt,
                                                 const int* __restrict__ ell,
                                                 const float* __restrict__ b2,
                                                 float* __restrict__ out) {
    int n = blockIdx.x;
    int c = threadIdx.x;
    float ald = aldp[n];
    int dg = cnt[n]; if (dg > ELLW) dg = ELLW;
    const int* ep = ell + (size_t)n * ELLW;
    float acc = 0.f, den = 0.f;
    int i = 0;
    for (; i + 4 <= dg; i += 4) {
        int s0 = ep[i], s1 = ep[i + 1], s2 = ep[i + 2], s3 = ep[i + 3];
        float e0 = als[s0], e1 = als[s1], e2 = als[s2], e3 = als[s3];
        float v0 = 0.f, v1 = 0.f, v2 = 0.f, v3 = 0.f;
        if (c < NCLS) {
            v0 = hx40[(size_t)s0 * NCLS + c];
            v1 = hx40[(size_t)s1 * NCLS + c];
            v2 = hx40[(size_t)s2 * NCLS + c];
            v3 = hx40[(size_t)s3 * NCLS + c];
        }
        e0 += ald; e0 = e0 > 0.f ? e0 : 0.2f * e0;
        e1 += ald; e1 = e1 > 0.f ? e1 : 0.2f * e1;
        e2 += ald; e2 = e2 > 0.f ? e2 : 0.2f * e2;
        e3 += ald; e3 = e3 > 0.f ? e3 : 0.2f * e3;
        float w0 = __expf(e0), w1 = __expf(e1), w2 = __expf(e2), w3 = __expf(e3);
        acc += w0 * v0 + w1 * v1 + w2 * v2 + w3 * v3;
        den += w0 + w1 + w2 + w3;
    }
    for (; i < dg; ++i) {
        int s = ep[i];
        float e = als[s] + ald;
        e = e > 0.f ? e : 0.2f * e;
        float wgt = __expf(e);
        if (c < NCLS) acc += wgt * hx40[(size_t)s * NCLS + c];
        den += wgt;
    }
    if (c < NCLS) out[(size_t)n * NCLS + c] = acc / (den + 1e-16f) + b2[c];
}

extern "C" void kernel_launch(void* const* d_in, const int* in_sizes, int n_in,
                              void* d_out, int out_size, void* d_ws, size_t ws_size,
                              hipStream_t stream) {
    const float* x   = (const float*)d_in[0];
    const int*   ei  = (const int*)  d_in[1];
    const float* W0  = (const float*)d_in[2];
    const float* as0 = (const float*)d_in[3];
    const float* ad0 = (const float*)d_in[4];
    const float* b0  = (const float*)d_in[5];
    const float* W1  = (const float*)d_in[6];
    const float* as1 = (const float*)d_in[7];
    const float* ad1 = (const float*)d_in[8];
    const float* b1  = (const float*)d_in[9];
    const float* W2  = (const float*)d_in[10];
    const float* as2 = (const float*)d_in[11];
    const float* ad2 = (const float*)d_in[12];
    const float* b2  = (const float*)d_in[13];
    float* out = (float*)d_out;

    char* p = (char*)d_ws;
    int* cnt  = (int*)p; p += 40064;
    int* ell  = (int*)p; p += (size_t)NN * ELLW * 4;    // 3.84 MB
    f16* w0T  = (f16*)p; p += HC * FIN * 2;
    f16* w1T  = (f16*)p; p += HC * HC * 2;
    f16* w2T  = (f16*)p; p += NCLS * HC * 2;
    f16* hxA  = (f16*)p; p += (size_t)NN * HC * 2;
    f16* hxB  = (f16*)p; p += (size_t)NN * HC * 2;
    f16* fA   = (f16*)p; p += (size_t)NN * HC * 2;
    f16* fB   = (f16*)p; p += (size_t)NN * HC * 2;
    float* hx40 = (float*)p; p += (size_t)NN * NCLS * 4;
    float* als0 = (float*)p; p += NN * HH * 4;
    float* ald0 = (float*)p; p += NN * HH * 4;
    float* als1 = (float*)p; p += NN * HH * 4;
    float* ald1 = (float*)p; p += NN * HH * 4;
    float* als2 = (float*)p; p += NN * 4;
    float* ald2 = (float*)p; p += NN * 4;

    const int NBR = (NN + 127) / 128;   // 79 row-chunks (layers 0/1)
    const int NAG = (NN + 3) / 4;       // 2500 blocks (wave-per-node agg)
    const int NB2 = (NN + 63) / 64;     // 157 row-blocks (layer 2)

    zero_int<<<(NN + 255) / 256, 256, 0, stream>>>(cnt, NN);
    scatter_ell<<<(ET + 255) / 256, 256, 0, stream>>>(ei, cnt, ell);
    convW_kernel<<<(HC * FIN + HC * HC + NCLS * HC + 255) / 256, 256, 0, stream>>>(
        W0, W1, W2, w0T, w1T, w2T);

    dim3 gA(4, NBR);   // 4 head-pairs x 79 row-chunks = 316 blocks
    // layer 0: GEMM(fp32 x -> f16 frags) + attn epilogue; then aggregate
    gemm_attn<FIN, true><<<gA, 512, 0, stream>>>(x, w0T, as0, ad0, hxA, als0, ald0);
    agg_ell<<<NAG, 256, 0, stream>>>(hxA, als0, ald0, cnt, ell, b0, fA);
    // layer 1
    gemm_attn<HC, false><<<gA, 512, 0, stream>>>(fA, w1T, as1, ad1, hxB, als1, ald1);
    agg_ell<<<NAG, 256, 0, stream>>>(hxB, als1, ald1, cnt, ell, b1, fB);
    // layer 2
    gemm2_attn<<<NB2, 256, 0, stream>>>(fB, w2T, as2, ad2, hx40, als2, ald2);
    agg2_final<<<NN, 64, 0, stream>>>(hx40, als2, ald2, cnt, ell, b2, out);
}

// Round 10
// 207.099 us; speedup vs baseline: 1.7375x; 1.0018x over previous
//
#include <hip/hip_runtime.h>
#include <math.h>

#define NN 10000
#define EE 160000
#define ET 170000
#define FIN 256
#define HH 8
#define CC 64
#define HC 512
#define NCLS 40
#define ELLW 96

typedef unsigned short u16;
typedef unsigned int u32;
typedef _Float16 f16;
using f16x8 = __attribute__((ext_vector_type(8))) _Float16;
using f32x4 = __attribute__((ext_vector_type(4))) float;

#define MFMA16(a, b, c) __builtin_amdgcn_mfma_f32_16x16x32_f16((a), (b), (c), 0, 0, 0)

// ---------- prep: weight transposes (fp32 [K][N] -> f16 [N][K]) + cnt zero ----
__global__ __launch_bounds__(256) void convW_kernel(const float* __restrict__ W0,
                                                    const float* __restrict__ W1,
                                                    const float* __restrict__ W2,
                                                    f16* __restrict__ w0T,
                                                    f16* __restrict__ w1T,
                                                    f16* __restrict__ w2T,
                                                    int* __restrict__ cnt) {
    int i = blockIdx.x * 256 + threadIdx.x;
    if (i < NN) cnt[i] = 0;                  // fold the zeroing launch in here
    if (i < HC * FIN) {
        int n = i >> 8, k = i & 255;
        w0T[i] = (f16)W0[(size_t)k * HC + n];
    } else if (i < HC * FIN + HC * HC) {
        int j = i - HC * FIN;
        int n = j >> 9, k = j & 511;
        w1T[j] = (f16)W1[(size_t)k * HC + n];
    } else if (i < HC * FIN + HC * HC + NCLS * HC) {
        int j = i - HC * FIN - HC * HC;
        int n = j >> 9, k = j & 511;
        w2T[j] = (f16)W2[(size_t)k * NCLS + n];
    }
}

__global__ __launch_bounds__(256) void scatter_ell(const int* __restrict__ ei,
                                                   int* __restrict__ cnt,
                                                   int* __restrict__ ell) {
    int e = blockIdx.x * 256 + threadIdx.x;
    if (e >= ET) return;
    int s, d;
    if (e < EE) { s = ei[e]; d = ei[EE + e]; }
    else        { s = e - EE; d = s; }          // self-loops appended
    int pos = atomicAdd(&cnt[d], 1);
    if (pos < ELLW) ell[(size_t)d * ELLW + pos] = s;
}

// ---------- GEMM + fused attn: B-resident LDS, barrier-free K-loop ----------
template <int K, bool AF32>
__global__ __launch_bounds__(512) void gemm_attn(const void* __restrict__ Aptr,
                                                 const f16* __restrict__ BT,
                                                 const float* __restrict__ a_src,
                                                 const float* __restrict__ a_dst,
                                                 f16* __restrict__ hx2,
                                                 float* __restrict__ al_s,
                                                 float* __restrict__ al_d) {
    constexpr int KK = K / 32;            // MFMA K-steps (16 or 8)
    constexpr int CH = K / 8;             // 16B chunks per B row (64 or 32)
    __shared__ f16 Bs[64 * K];            // 64 KB (K=512) / 32 KB (K=256)
    int t = threadIdx.x;
    int hp = blockIdx.x;                  // head pair
    int lane = t & 63, w = t >> 6;
    int fm = lane & 15, g = lane >> 4;
    int bm = blockIdx.y * 128 + w * 16;
    int row = bm + fm;
    bool rok = row < NN;

    f16x8 af[KK];
    if (AF32) {
        const float* A = (const float*)Aptr;
#pragma unroll
        for (int kk = 0; kk < KK; ++kk) {
            float4 lo = make_float4(0.f, 0.f, 0.f, 0.f), hi = lo;
            if (rok) {
                const float* ap = A + (size_t)row * K + kk * 32 + g * 8;
                lo = *(const float4*)ap;
                hi = *(const float4*)(ap + 4);
            }
            f16x8 v;
            v[0] = (f16)lo.x; v[1] = (f16)lo.y; v[2] = (f16)lo.z; v[3] = (f16)lo.w;
            v[4] = (f16)hi.x; v[5] = (f16)hi.y; v[6] = (f16)hi.z; v[7] = (f16)hi.w;
            af[kk] = v;
        }
    } else {
        const f16* A = (const f16*)Aptr;
#pragma unroll
        for (int kk = 0; kk < KK; ++kk) {
            uint4 r = rok ? *(const uint4*)(A + (size_t)row * K + kk * 32 + g * 8)
                          : make_uint4(0u, 0u, 0u, 0u);
            af[kk] = __builtin_bit_cast(f16x8, r);
        }
    }

    for (int sl = 0; sl < 2; ++sl) {
        int h = hp * 2 + sl;
        const f16* bsrc = BT + (size_t)h * 64 * K;
        for (int c = t; c < 64 * CH; c += 512) {
            int brow = c / CH;
            int j = c - brow * CH;
            uint4 v = *(const uint4*)(bsrc + (size_t)brow * K + j * 8);
            *(uint4*)&Bs[(size_t)brow * K + ((j ^ (brow & 7)) * 8)] = v;
        }
        __syncthreads();

        f32x4 acc[4] = {};
#pragma unroll
        for (int kk = 0; kk < KK; ++kk) {
#pragma unroll
            for (int nt = 0; nt < 4; ++nt) {
                f16x8 b = *(const f16x8*)
                    &Bs[(nt * 16 + fm) * K + (((kk * 4 + g) ^ (fm & 7)) * 8)];
                acc[nt] = MFMA16(af[kk], b, acc[nt]);
            }
        }

        float asc[4], adc[4];
#pragma unroll
        for (int nt = 0; nt < 4; ++nt) {
            asc[nt] = a_src[h * 64 + nt * 16 + fm];
            adc[nt] = a_dst[h * 64 + nt * 16 + fm];
        }
#pragma unroll
        for (int r = 0; r < 4; ++r) {
            int orow = bm + g * 4 + r;          // C/D: row=(lane>>4)*4+reg
            float s = acc[0][r] * asc[0] + acc[1][r] * asc[1] +
                      acc[2][r] * asc[2] + acc[3][r] * asc[3];
            float d = acc[0][r] * adc[0] + acc[1][r] * adc[1] +
                      acc[2][r] * adc[2] + acc[3][r] * adc[3];
#pragma unroll
            for (int off = 1; off < 16; off <<= 1) {
                s += __shfl_xor(s, off);
                d += __shfl_xor(d, off);
            }
            if (orow < NN) {
                if (fm == 0) {
                    al_s[orow * 8 + h] = s;
                    al_d[orow * 8 + h] = d;
                }
#pragma unroll
                for (int nt = 0; nt < 4; ++nt)
                    hx2[(size_t)orow * HC + h * 64 + nt * 16 + fm] =
                        (f16)acc[nt][r];
            }
        }
        __syncthreads();
    }
}

// ---------- layer 2: barrier-free B-resident GEMM 512->40 + fused attn ------
__global__ __launch_bounds__(256) void gemm2_attn(const f16* __restrict__ A,
                                                  const f16* __restrict__ BT,
                                                  const float* __restrict__ a_src2,
                                                  const float* __restrict__ a_dst2,
                                                  float* __restrict__ hx40,
                                                  float* __restrict__ als2,
                                                  float* __restrict__ ald2) {
    __shared__ f16 Bs[48 * HC];    // 48 KB, rows 40..47 zero
    int t = threadIdx.x;
    int lane = t & 63, w = t >> 6;
    int fm = lane & 15, g = lane >> 4;
    int bm = blockIdx.x * 64 + w * 16;
    int row = bm + fm;
    bool rok = row < NN;

    for (int c = t; c < 48 * 64; c += 256) {
        int brow = c >> 6, j = c & 63;
        uint4 v = make_uint4(0u, 0u, 0u, 0u);
        if (brow < NCLS) v = *(const uint4*)(BT + (size_t)brow * HC + j * 8);
        *(uint4*)&Bs[brow * HC + ((j ^ (brow & 7)) * 8)] = v;
    }

    f16x8 af[16];
#pragma unroll
    for (int kk = 0; kk < 16; ++kk) {
        uint4 r = rok ? *(const uint4*)(A + (size_t)row * HC + kk * 32 + g * 8)
                      : make_uint4(0u, 0u, 0u, 0u);
        af[kk] = __builtin_bit_cast(f16x8, r);
    }
    __syncthreads();

    f32x4 acc[3] = {};
#pragma unroll
    for (int kk = 0; kk < 16; ++kk) {
#pragma unroll
        for (int nt = 0; nt < 3; ++nt) {
            f16x8 b = *(const f16x8*)
                &Bs[(nt * 16 + fm) * HC + (((kk * 4 + g) ^ (fm & 7)) * 8)];
            acc[nt] = MFMA16(af[kk], b, acc[nt]);
        }
    }

    float a2s[3], a2d[3];
#pragma unroll
    for (int nt = 0; nt < 3; ++nt) {
        int col = nt * 16 + fm;
        a2s[nt] = (col < NCLS) ? a_src2[col] : 0.f;
        a2d[nt] = (col < NCLS) ? a_dst2[col] : 0.f;
    }
#pragma unroll
    for (int r = 0; r < 4; ++r) {
        int orow = bm + g * 4 + r;
        float s = acc[0][r] * a2s[0] + acc[1][r] * a2s[1] + acc[2][r] * a2s[2];
        float d = acc[0][r] * a2d[0] + acc[1][r] * a2d[1] + acc[2][r] * a2d[2];
#pragma unroll
        for (int off = 1; off < 16; off <<= 1) {
            s += __shfl_xor(s, off);
            d += __shfl_xor(d, off);
        }
        if (orow < NN) {
            if (fm == 0) { als2[orow] = s; ald2[orow] = d; }
#pragma unroll
            for (int nt = 0; nt < 3; ++nt) {
                int col = nt * 16 + fm;
                if (col < NCLS) hx40[(size_t)orow * NCLS + col] = acc[nt][r];
            }
        }
    }
}

// ---------- aggregate: 2 WAVES per node (even/odd ELL slots), LDS combine ----
// block = 256 thr = 2 nodes x 2 waves. Each wave: 8 ch/lane via uint4 loads,
// strided (step 2) edge loop unrolled x4 -> 4 independent gather chains and
// half the per-node serial latency vs 1-wave-per-node.
__global__ __launch_bounds__(256) void agg_ell(const f16* __restrict__ hx2,
                                               const float* __restrict__ al_s,
                                               const float* __restrict__ al_d,
                                               const int* __restrict__ cnt,
                                               const int* __restrict__ ell,
                                               const float* __restrict__ bias,
                                               f16* __restrict__ outF) {
    __shared__ float accbuf[2][64][8];
    __shared__ float denbuf[2][64];
    int t = threadIdx.x;
    int lane = t & 63, w = t >> 6;
    int p = w >> 1, sub = w & 1;
    int n = blockIdx.x * 2 + p;
    bool nok = n < NN;
    int ch = lane * 8;          // 8 channels per lane; 64 lanes = 512 ch
    int h = lane >> 3;
    float acc[8] = {0.f, 0.f, 0.f, 0.f, 0.f, 0.f, 0.f, 0.f};
    float den = 0.f;
    if (nok) {
        float ald = al_d[n * HH + h];
        int dg = cnt[n]; if (dg > ELLW) dg = ELLW;
        const int* ep = ell + (size_t)n * ELLW;
        int i = sub;
        for (; i + 6 < dg; i += 8) {     // edges i, i+2, i+4, i+6
            int s0 = ep[i], s1 = ep[i + 2], s2 = ep[i + 4], s3 = ep[i + 6];
            float e0 = al_s[s0 * HH + h], e1 = al_s[s1 * HH + h];
            float e2 = al_s[s2 * HH + h], e3 = al_s[s3 * HH + h];
            uint4 v0 = *(const uint4*)(hx2 + (size_t)s0 * HC + ch);
            uint4 v1 = *(const uint4*)(hx2 + (size_t)s1 * HC + ch);
            uint4 v2 = *(const uint4*)(hx2 + (size_t)s2 * HC + ch);
            uint4 v3 = *(const uint4*)(hx2 + (size_t)s3 * HC + ch);
            e0 += ald; e0 = e0 > 0.f ? e0 : 0.2f * e0;
            e1 += ald; e1 = e1 > 0.f ? e1 : 0.2f * e1;
            e2 += ald; e2 = e2 > 0.f ? e2 : 0.2f * e2;
            e3 += ald; e3 = e3 > 0.f ? e3 : 0.2f * e3;
            float w0 = __expf(e0), w1 = __expf(e1);
            float w2 = __expf(e2), w3 = __expf(e3);
            f16x8 f0 = __builtin_bit_cast(f16x8, v0);
            f16x8 f1 = __builtin_bit_cast(f16x8, v1);
            f16x8 f2 = __builtin_bit_cast(f16x8, v2);
            f16x8 f3 = __builtin_bit_cast(f16x8, v3);
#pragma unroll
            for (int j = 0; j < 8; ++j)
                acc[j] += w0 * (float)f0[j] + w1 * (float)f1[j] +
                          w2 * (float)f2[j] + w3 * (float)f3[j];
            den += w0 + w1 + w2 + w3;
        }
        for (; i < dg; i += 2) {
            int s = ep[i];
            float e = al_s[s * HH + h] + ald;
            e = e > 0.f ? e : 0.2f * e;
            float wgt = __expf(e);
            uint4 v = *(const uint4*)(hx2 + (size_t)s * HC + ch);
            f16x8 f = __builtin_bit_cast(f16x8, v);
#pragma unroll
            for (int j = 0; j < 8; ++j) acc[j] += wgt * (float)f[j];
            den += wgt;
        }
    }
    if (sub == 1) {
#pragma unroll
        for (int j = 0; j < 8; ++j) accbuf[p][lane][j] = acc[j];
        denbuf[p][lane] = den;
    }
    __syncthreads();
    if (sub == 0 && nok) {
#pragma unroll
        for (int j = 0; j < 8; ++j) acc[j] += accbuf[p][lane][j];
        den += denbuf[p][lane];
        float inv = 1.f / (den + 1e-16f);
        float4 b0v = *(const float4*)(bias + ch);
        float4 b1v = *(const float4*)(bias + ch + 4);
        float bb[8] = {b0v.x, b0v.y, b0v.z, b0v.w, b1v.x, b1v.y, b1v.z, b1v.w};
        f16x8 o;
#pragma unroll
        for (int j = 0; j < 8; ++j) {
            float v = acc[j] * inv + bb[j];
            v = v > 0.f ? v : expm1f(v);        // ELU
            o[j] = (f16)v;
        }
        *(uint4*)(outF + (size_t)n * HC + ch) = __builtin_bit_cast(uint4, o);
    }
}

// ---------- final aggregate (H=1, C=40), fp32, no ELU ----------
__global__ __launch_bounds__(64) void agg2_final(const float* __restrict__ hx40,
                                                 const float* __restrict__ als,
                                                 const float* __restrict__ aldp,
                                                 const int* __restrict__ cnt,
                                                 const int* __restrict__ ell,
                                                 const float* __restrict__ b2,
                                                 float* __restrict__ out) {
    int n = blockIdx.x;
    int c = threadIdx.x;
    float ald = aldp[n];
    int dg = cnt[n]; if (dg > ELLW) dg = ELLW;
    const int* ep = ell + (size_t)n * ELLW;
    float acc = 0.f, den = 0.f;
    int i = 0;
    for (; i + 4 <= dg; i += 4) {
        int s0 = ep[i], s1 = ep[i + 1], s2 = ep[i + 2], s3 = ep[i + 3];
        float e0 = als[s0], e1 = als[s1], e2 = als[s2], e3 = als[s3];
        float v0 = 0.f, v1 = 0.f, v2 = 0.f, v3 = 0.f;
        if (c < NCLS) {
            v0 = hx40[(size_t)s0 * NCLS + c];
            v1 = hx40[(size_t)s1 * NCLS + c];
            v2 = hx40[(size_t)s2 * NCLS + c];
            v3 = hx40[(size_t)s3 * NCLS + c];
        }
        e0 += ald; e0 = e0 > 0.f ? e0 : 0.2f * e0;
        e1 += ald; e1 = e1 > 0.f ? e1 : 0.2f * e1;
        e2 += ald; e2 = e2 > 0.f ? e2 : 0.2f * e2;
        e3 += ald; e3 = e3 > 0.f ? e3 : 0.2f * e3;
        float w0 = __expf(e0), w1 = __expf(e1), w2 = __expf(e2), w3 = __expf(e3);
        acc += w0 * v0 + w1 * v1 + w2 * v2 + w3 * v3;
        den += w0 + w1 + w2 + w3;
    }
    for (; i < dg; ++i) {
        int s = ep[i];
        float e = als[s] + ald;
        e = e > 0.f ? e : 0.2f * e;
        float wgt = __expf(e);
        if (c < NCLS) acc += wgt * hx40[(size_t)s * NCLS + c];
        den += wgt;
    }
    if (c < NCLS) out[(size_t)n * NCLS + c] = acc / (den + 1e-16f) + b2[c];
}

extern "C" void kernel_launch(void* const* d_in, const int* in_sizes, int n_in,
                              void* d_out, int out_size, void* d_ws, size_t ws_size,
                              hipStream_t stream) {
    const float* x   = (const float*)d_in[0];
    const int*   ei  = (const int*)  d_in[1];
    const float* W0  = (const float*)d_in[2];
    const float* as0 = (const float*)d_in[3];
    const float* ad0 = (const float*)d_in[4];
    const float* b0  = (const float*)d_in[5];
    const float* W1  = (const float*)d_in[6];
    const float* as1 = (const float*)d_in[7];
    const float* ad1 = (const float*)d_in[8];
    const float* b1  = (const float*)d_in[9];
    const float* W2  = (const float*)d_in[10];
    const float* as2 = (const float*)d_in[11];
    const float* ad2 = (const float*)d_in[12];
    const float* b2  = (const float*)d_in[13];
    float* out = (float*)d_out;

    char* p = (char*)d_ws;
    int* cnt  = (int*)p; p += 40064;
    int* ell  = (int*)p; p += (size_t)NN * ELLW * 4;    // 3.84 MB
    f16* w0T  = (f16*)p; p += HC * FIN * 2;
    f16* w1T  = (f16*)p; p += HC * HC * 2;
    f16* w2T  = (f16*)p; p += NCLS * HC * 2;
    f16* hxA  = (f16*)p; p += (size_t)NN * HC * 2;
    f16* hxB  = (f16*)p; p += (size_t)NN * HC * 2;
    f16* fA   = (f16*)p; p += (size_t)NN * HC * 2;
    f16* fB   = (f16*)p; p += (size_t)NN * HC * 2;
    float* hx40 = (float*)p; p += (size_t)NN * NCLS * 4;
    float* als0 = (float*)p; p += NN * HH * 4;
    float* ald0 = (float*)p; p += NN * HH * 4;
    float* als1 = (float*)p; p += NN * HH * 4;
    float* ald1 = (float*)p; p += NN * HH * 4;
    float* als2 = (float*)p; p += NN * 4;
    float* ald2 = (float*)p; p += NN * 4;

    const int NBR = (NN + 127) / 128;   // 79 row-chunks (layers 0/1)
    const int NAG = (NN + 1) / 2;       // 5000 blocks (2 waves/node agg)
    const int NB2 = (NN + 63) / 64;     // 157 row-blocks (layer 2)

    convW_kernel<<<(HC * FIN + HC * HC + NCLS * HC + 255) / 256, 256, 0, stream>>>(
        W0, W1, W2, w0T, w1T, w2T, cnt);
    scatter_ell<<<(ET + 255) / 256, 256, 0, stream>>>(ei, cnt, ell);

    dim3 gA(4, NBR);   // 4 head-pairs x 79 row-chunks = 316 blocks
    // layer 0: GEMM(fp32 x -> f16 frags) + attn epilogue; then aggregate
    gemm_attn<FIN, true><<<gA, 512, 0, stream>>>(x, w0T, as0, ad0, hxA, als0, ald0);
    agg_ell<<<NAG, 256, 0, stream>>>(hxA, als0, ald0, cnt, ell, b0, fA);
    // layer 1
    gemm_attn<HC, false><<<gA, 512, 0, stream>>>(fA, w1T, as1, ad1, hxB, als1, ald1);
    agg_ell<<<NAG, 256, 0, stream>>>(hxB, als1, ald1, cnt, ell, b1, fB);
    // layer 2
    gemm2_attn<<<NB2, 256, 0, stream>>>(fB, w2T, as2, ad2, hx40, als2, ald2);
    agg2_final<<<NN, 64, 0, stream>>>(hx40, als2, ald2, cnt, ell, b2, out);
}